// Round 1
// baseline (1020.865 us; speedup 1.0000x reference)
//
#include <hip/hip_runtime.h>

// ---------------------------------------------------------------------------
// Net_60129542953: GCN(128->256) + BN + ReLU + GCN(256->128) + LN + ReLU +
// Linear(128->128), then per-pair dot decode + threshold.
// All f32. CSR-by-dst built on device for deterministic aggregation.
// ---------------------------------------------------------------------------

#define C_IN  128
#define C_HID 256
#define C_OUT 128

// ---------------- CSR build ----------------

__global__ __launch_bounds__(256) void hist_kernel(const int* __restrict__ dst,
                                                   int* __restrict__ counts, int E) {
  int e = blockIdx.x * 256 + threadIdx.x;
  if (e < E) atomicAdd(&counts[dst[e]], 1);
}

__global__ __launch_bounds__(256) void dinv_kernel(const int* __restrict__ counts,
                                                   float* __restrict__ dinv,
                                                   int* __restrict__ cursor, int N) {
  int n = blockIdx.x * 256 + threadIdx.x;
  if (n < N) {
    dinv[n] = rsqrtf((float)counts[n] + 1.0f);  // deg = indeg + 1 (self loop)
    cursor[n] = 0;
  }
}

// single-block exclusive scan of counts[0..n) -> row_ptr[0..n]
__global__ __launch_bounds__(1024) void scan_kernel(const int* __restrict__ counts,
                                                    int* __restrict__ row_ptr, int n) {
  __shared__ int wsum[16];
  int tid = threadIdx.x;
  int lane = tid & 63, wid = tid >> 6;
  int carry = 0;  // only tid 0's copy is meaningful
  for (int base = 0; base <= n; base += 1024) {
    int idx = base + tid;
    int v = (idx < n) ? counts[idx] : 0;
    int x = v;
#pragma unroll
    for (int d = 1; d < 64; d <<= 1) {
      int y = __shfl_up(x, d, 64);
      if (lane >= d) x += y;
    }
    if (lane == 63) wsum[wid] = x;
    __syncthreads();
    if (tid == 0) {
      int run = carry;
#pragma unroll
      for (int w = 0; w < 16; ++w) { int t = wsum[w]; wsum[w] = run; run += t; }
      carry = run;
    }
    __syncthreads();
    if (idx <= n) row_ptr[idx] = wsum[wid] + x - v;  // exclusive
    __syncthreads();  // protect wsum before next iteration overwrites
  }
}

__global__ __launch_bounds__(256) void place_kernel(const int* __restrict__ src,
                                                    const int* __restrict__ dst,
                                                    const int* __restrict__ row_ptr,
                                                    int* __restrict__ cursor,
                                                    int* __restrict__ srcs, int E) {
  int e = blockIdx.x * 256 + threadIdx.x;
  if (e < E) {
    int d = dst[e];
    int pos = row_ptr[d] + atomicAdd(&cursor[d], 1);
    srcs[pos] = src[e];
  }
}

// ---------------- f32 GEMM: C[M,N] = A[M,K] @ B[K,N] (+bias) ----------------
// 128x64 tile, BK=16, 256 threads, 8x4 micro-tile per thread.

#define GBM 128
#define GBN 64
#define GBK 16

__global__ __launch_bounds__(256) void sgemm_kernel(const float* __restrict__ A,
                                                    const float* __restrict__ B,
                                                    const float* __restrict__ bias,
                                                    float* __restrict__ C,
                                                    int M, int N, int K) {
  __shared__ float As[GBM][GBK];  // 8 KB
  __shared__ float Bs[GBK][GBN];  // 4 KB
  int tid = threadIdx.x;
  int tx = tid & 15;   // col group: cols tx*4 .. +3
  int ty = tid >> 4;   // row group: rows ty*8 .. +7
  int rowBase = blockIdx.y * GBM;
  int colBase = blockIdx.x * GBN;

  float acc[8][4];
#pragma unroll
  for (int i = 0; i < 8; ++i)
#pragma unroll
    for (int j = 0; j < 4; ++j) acc[i][j] = 0.0f;

  for (int k0 = 0; k0 < K; k0 += GBK) {
    // A tile: 128x16 = 512 float4, 2 per thread (ds_write_b128, sequential)
#pragma unroll
    for (int it = 0; it < 2; ++it) {
      int f = tid + it * 256;
      int m = f >> 2, k4 = (f & 3) << 2;
      int gm = rowBase + m;
      float4 v = make_float4(0.f, 0.f, 0.f, 0.f);
      if (gm < M) v = *(const float4*)&A[(size_t)gm * K + k0 + k4];
      *(float4*)&As[m][k4] = v;
    }
    // B tile: 16x64 = 256 float4, 1 per thread
    {
      int n4 = (tid & 15) << 2, k = tid >> 4;
      float4 v = *(const float4*)&B[(size_t)(k0 + k) * N + colBase + n4];
      *(float4*)&Bs[k][n4] = v;
    }
    __syncthreads();
#pragma unroll
    for (int k4 = 0; k4 < 4; ++k4) {
      float4 b0 = *(float4*)&Bs[k4 * 4 + 0][tx * 4];
      float4 b1 = *(float4*)&Bs[k4 * 4 + 1][tx * 4];
      float4 b2 = *(float4*)&Bs[k4 * 4 + 2][tx * 4];
      float4 b3 = *(float4*)&Bs[k4 * 4 + 3][tx * 4];
#pragma unroll
      for (int i = 0; i < 8; ++i) {
        float4 a = *(float4*)&As[ty * 8 + i][k4 * 4];
        acc[i][0] += a.x * b0.x + a.y * b1.x + a.z * b2.x + a.w * b3.x;
        acc[i][1] += a.x * b0.y + a.y * b1.y + a.z * b2.y + a.w * b3.y;
        acc[i][2] += a.x * b0.z + a.y * b1.z + a.z * b2.z + a.w * b3.z;
        acc[i][3] += a.x * b0.w + a.y * b1.w + a.z * b2.w + a.w * b3.w;
      }
    }
    __syncthreads();
  }

  float4 bv = make_float4(0.f, 0.f, 0.f, 0.f);
  if (bias) bv = *(const float4*)&bias[colBase + tx * 4];
#pragma unroll
  for (int i = 0; i < 8; ++i) {
    int gm = rowBase + ty * 8 + i;
    if (gm < M) {
      float4 o = make_float4(acc[i][0] + bv.x, acc[i][1] + bv.y,
                             acc[i][2] + bv.z, acc[i][3] + bv.w);
      *(float4*)&C[(size_t)gm * N + colBase + tx * 4] = o;
    }
  }
}

// ---------------- Edge aggregation (one wave per node) ----------------
// out[n] = sum_{e: dst=n} h[src_e] * dinv[src_e]*dinv[n]  +  h[n]*dinv[n]^2 + bias

__global__ __launch_bounds__(256) void agg256_kernel(const float* __restrict__ h,
                                                     const float* __restrict__ dinv,
                                                     const int* __restrict__ row_ptr,
                                                     const int* __restrict__ srcs,
                                                     const float* __restrict__ bias,
                                                     float* __restrict__ out, int N) {
  int gw = (blockIdx.x * 256 + threadIdx.x) >> 6;
  int lane = threadIdx.x & 63;
  if (gw >= N) return;
  float dn = dinv[gw];
  int e0 = row_ptr[gw], e1 = row_ptr[gw + 1];
  const float4* h4 = (const float4*)h;
  float4 acc = make_float4(0.f, 0.f, 0.f, 0.f);
  for (int e = e0; e < e1; ++e) {
    int s = srcs[e];
    float w = dinv[s] * dn;
    float4 v = h4[(size_t)s * 64 + lane];
    acc.x += v.x * w; acc.y += v.y * w; acc.z += v.z * w; acc.w += v.w * w;
  }
  {
    float w = dn * dn;
    float4 v = h4[(size_t)gw * 64 + lane];
    acc.x += v.x * w; acc.y += v.y * w; acc.z += v.z * w; acc.w += v.w * w;
  }
  float4 b = ((const float4*)bias)[lane];
  acc.x += b.x; acc.y += b.y; acc.z += b.z; acc.w += b.w;
  ((float4*)out)[(size_t)gw * 64 + lane] = acc;
}

__global__ __launch_bounds__(256) void agg128_kernel(const float* __restrict__ h,
                                                     const float* __restrict__ dinv,
                                                     const int* __restrict__ row_ptr,
                                                     const int* __restrict__ srcs,
                                                     const float* __restrict__ bias,
                                                     float* __restrict__ out, int N) {
  int gw = (blockIdx.x * 256 + threadIdx.x) >> 6;
  int lane = threadIdx.x & 63;
  if (gw >= N) return;
  float dn = dinv[gw];
  int e0 = row_ptr[gw], e1 = row_ptr[gw + 1];
  const float2* h2 = (const float2*)h;
  float2 acc = make_float2(0.f, 0.f);
  for (int e = e0; e < e1; ++e) {
    int s = srcs[e];
    float w = dinv[s] * dn;
    float2 v = h2[(size_t)s * 64 + lane];
    acc.x += v.x * w; acc.y += v.y * w;
  }
  {
    float w = dn * dn;
    float2 v = h2[(size_t)gw * 64 + lane];
    acc.x += v.x * w; acc.y += v.y * w;
  }
  float2 b = ((const float2*)bias)[lane];
  acc.x += b.x; acc.y += b.y;
  ((float2*)out)[(size_t)gw * 64 + lane] = acc;
}

// ---------------- BatchNorm (over nodes, per channel) ----------------

__global__ __launch_bounds__(256) void bn_stats_kernel(const float* __restrict__ h,
                                                       float* __restrict__ sums, int N) {
  int c = threadIdx.x;  // 256 channels
  int rows_per = (N + gridDim.x - 1) / gridDim.x;
  int r0 = blockIdx.x * rows_per;
  int r1 = min(N, r0 + rows_per);
  float s = 0.f, ss = 0.f;
  for (int r = r0; r < r1; ++r) {
    float v = h[(size_t)r * C_HID + c];
    s += v; ss += v * v;
  }
  atomicAdd(&sums[c], s);
  atomicAdd(&sums[C_HID + c], ss);
}

__global__ __launch_bounds__(256) void bn_apply_kernel(float* __restrict__ h,
                                                       const float* __restrict__ sums,
                                                       const float* __restrict__ gamma,
                                                       const float* __restrict__ beta, int N) {
  int c = threadIdx.x;
  float invN = 1.0f / (float)N;
  float mu = sums[c] * invN;
  float var = sums[C_HID + c] * invN - mu * mu;
  float sc = gamma[c] * rsqrtf(var + 1e-5f);
  float sh = beta[c] - mu * sc;
  int rows_per = (N + gridDim.x - 1) / gridDim.x;
  int r0 = blockIdx.x * rows_per;
  int r1 = min(N, r0 + rows_per);
  for (int r = r0; r < r1; ++r) {
    size_t idx = (size_t)r * C_HID + c;
    h[idx] = fmaxf(h[idx] * sc + sh, 0.0f);
  }
}

// ---------------- LayerNorm + ReLU (one wave per row of 128) ----------------

__global__ __launch_bounds__(256) void ln_relu_kernel(float* __restrict__ h,
                                                      const float* __restrict__ gamma,
                                                      const float* __restrict__ beta, int N) {
  int gw = (blockIdx.x * 256 + threadIdx.x) >> 6;
  int lane = threadIdx.x & 63;
  if (gw >= N) return;
  float2* h2 = (float2*)h;
  float2 v = h2[(size_t)gw * 64 + lane];
  float s = v.x + v.y;
  float ss = v.x * v.x + v.y * v.y;
#pragma unroll
  for (int d = 1; d < 64; d <<= 1) {
    s += __shfl_xor(s, d, 64);
    ss += __shfl_xor(ss, d, 64);
  }
  float mu = s * (1.0f / C_OUT);
  float var = ss * (1.0f / C_OUT) - mu * mu;
  float rs = rsqrtf(var + 1e-5f);
  int c = lane * 2;
  float o0 = fmaxf((v.x - mu) * rs * gamma[c] + beta[c], 0.0f);
  float o1 = fmaxf((v.y - mu) * rs * gamma[c + 1] + beta[c + 1], 0.0f);
  h2[(size_t)gw * 64 + lane] = make_float2(o0, o1);
}

// ---------------- Decode (one wave per pair) ----------------

__global__ __launch_bounds__(256) void decode_kernel(const float* __restrict__ z,
                                                     const int* __restrict__ eli,
                                                     const float* __restrict__ cutoff,
                                                     float* __restrict__ out, int EL) {
  int gw = (blockIdx.x * 256 + threadIdx.x) >> 6;
  int lane = threadIdx.x & 63;
  if (gw >= EL) return;
  int a = eli[gw];
  int b = eli[EL + gw];
  const float2* z2 = (const float2*)z;
  float2 va = z2[(size_t)a * 64 + lane];
  float2 vb = z2[(size_t)b * 64 + lane];
  float s = va.x * vb.x + va.y * vb.y;
#pragma unroll
  for (int d = 1; d < 64; d <<= 1) s += __shfl_xor(s, d, 64);
  if (lane == 0) {
    out[gw] = s;
    out[EL + gw] = (s < cutoff[0]) ? 0.0f : 1.0f;
  }
}

// ---------------- Launch ----------------

extern "C" void kernel_launch(void* const* d_in, const int* in_sizes, int n_in,
                              void* d_out, int out_size, void* d_ws, size_t ws_size,
                              hipStream_t stream) {
  const float* x        = (const float*)d_in[0];
  const int*   eidx     = (const int*)d_in[1];
  const int*   eli      = (const int*)d_in[2];
  const float* cutoff   = (const float*)d_in[3];
  const float* W1       = (const float*)d_in[4];
  const float* b1       = (const float*)d_in[5];
  const float* bn_gamma = (const float*)d_in[6];
  const float* bn_beta  = (const float*)d_in[7];
  const float* W2       = (const float*)d_in[8];
  const float* b2       = (const float*)d_in[9];
  const float* ln_gamma = (const float*)d_in[10];
  const float* ln_beta  = (const float*)d_in[11];
  const float* lin_W    = (const float*)d_in[12];
  const float* lin_b    = (const float*)d_in[13];
  float* out = (float*)d_out;

  const int N  = in_sizes[0] / C_IN;   // 100000
  const int E  = in_sizes[1] / 2;      // 800000
  const int EL = in_sizes[2] / 2;      // 200000

  const int* src = eidx;
  const int* dst = eidx + E;

  // workspace layout (16B aligned segments)
  char* ws = (char*)d_ws;
  float* buf1 = (float*)ws;                 ws += (size_t)N * C_HID * 4;  // h1 -> h2 -> zlin
  float* buf2 = (float*)ws;                 ws += (size_t)N * C_HID * 4;  // agg1/h1n -> agg2/z
  float* dinv = (float*)ws;                 ws += (size_t)N * 4;
  int* counts = (int*)ws;                   ws += (size_t)N * 4;
  int* row_ptr = (int*)ws;                  ws += (size_t)(N + 4) * 4;
  int* cursor = (int*)ws;                   ws += (size_t)N * 4;
  int* srcs = (int*)ws;                     ws += (size_t)E * 4;
  float* sums = (float*)ws;                 ws += 2 * C_HID * 4;

  hipMemsetAsync(counts, 0, (size_t)N * 4, stream);
  hipMemsetAsync(sums, 0, 2 * C_HID * 4, stream);

  int eb = (E + 255) / 256;
  int nb = (N + 255) / 256;

  hist_kernel<<<eb, 256, 0, stream>>>(dst, counts, E);
  dinv_kernel<<<nb, 256, 0, stream>>>(counts, dinv, cursor, N);
  scan_kernel<<<1, 1024, 0, stream>>>(counts, row_ptr, N);
  place_kernel<<<eb, 256, 0, stream>>>(src, dst, row_ptr, cursor, srcs, E);

  dim3 g1(C_HID / GBN, (N + GBM - 1) / GBM);
  sgemm_kernel<<<g1, 256, 0, stream>>>(x, W1, nullptr, buf1, N, C_HID, C_IN);

  int wb = ((size_t)N * 64 + 255) / 256;
  agg256_kernel<<<wb, 256, 0, stream>>>(buf1, dinv, row_ptr, srcs, b1, buf2, N);

  bn_stats_kernel<<<512, 256, 0, stream>>>(buf2, sums, N);
  bn_apply_kernel<<<1024, 256, 0, stream>>>(buf2, sums, bn_gamma, bn_beta, N);

  dim3 g2(C_OUT / GBN, (N + GBM - 1) / GBM);
  sgemm_kernel<<<g2, 256, 0, stream>>>(buf2, W2, nullptr, buf1, N, C_OUT, C_HID);

  agg128_kernel<<<wb, 256, 0, stream>>>(buf1, dinv, row_ptr, srcs, b2, buf2, N);

  ln_relu_kernel<<<wb, 256, 0, stream>>>(buf2, ln_gamma, ln_beta, N);

  dim3 g3(C_OUT / GBN, (N + GBM - 1) / GBM);
  sgemm_kernel<<<g3, 256, 0, stream>>>(buf2, lin_W, lin_b, buf1, N, C_OUT, C_OUT);

  int db = ((size_t)EL * 64 + 255) / 256;
  decode_kernel<<<db, 256, 0, stream>>>(buf1, eli, cutoff, out, EL);
}

// Round 2
// 753.800 us; speedup vs baseline: 1.3543x; 1.3543x over previous
//
#include <hip/hip_runtime.h>
#include <stdint.h>

// ---------------------------------------------------------------------------
// Net_60129542953: GCN(128->256) + BN + ReLU + GCN(256->128) + LN + ReLU +
// Linear(128->128), then per-pair dot decode + threshold.
// R1: GEMMs moved to bf16 MFMA (16x16x32), global_load_lds width-16 staging.
// Aggregation/BN/LN/decode stay f32; BN/LN write bf16 for the next GEMM.
// ---------------------------------------------------------------------------

#define C_IN  128
#define C_HID 256
#define C_OUT 128

typedef __attribute__((ext_vector_type(8))) short bf16x8;
typedef __attribute__((ext_vector_type(4))) float f32x4;

__device__ __forceinline__ short f2bf(float f) {
  union { float f; uint32_t u; } v; v.f = f;
  uint32_t r = v.u + 0x7FFFu + ((v.u >> 16) & 1u);  // RNE
  return (short)(r >> 16);
}

__device__ __forceinline__ void async_cp16(const void* g, void* l) {
  __builtin_amdgcn_global_load_lds((const __attribute__((address_space(1))) void*)g,
                                   (__attribute__((address_space(3))) void*)l, 16, 0, 0);
}

// ---------------- CSR build ----------------

__global__ __launch_bounds__(256) void hist_kernel(const int* __restrict__ dst,
                                                   int* __restrict__ counts, int E) {
  int e = blockIdx.x * 256 + threadIdx.x;
  if (e < E) atomicAdd(&counts[dst[e]], 1);
}

__global__ __launch_bounds__(256) void dinv_kernel(const int* __restrict__ counts,
                                                   float* __restrict__ dinv,
                                                   int* __restrict__ cursor, int N) {
  int n = blockIdx.x * 256 + threadIdx.x;
  if (n < N) {
    dinv[n] = rsqrtf((float)counts[n] + 1.0f);  // deg = indeg + 1 (self loop)
    cursor[n] = 0;
  }
}

__global__ __launch_bounds__(1024) void scan_kernel(const int* __restrict__ counts,
                                                    int* __restrict__ row_ptr, int n) {
  __shared__ int wsum[16];
  int tid = threadIdx.x;
  int lane = tid & 63, wid = tid >> 6;
  int carry = 0;
  for (int base = 0; base <= n; base += 1024) {
    int idx = base + tid;
    int v = (idx < n) ? counts[idx] : 0;
    int x = v;
#pragma unroll
    for (int d = 1; d < 64; d <<= 1) {
      int y = __shfl_up(x, d, 64);
      if (lane >= d) x += y;
    }
    if (lane == 63) wsum[wid] = x;
    __syncthreads();
    if (tid == 0) {
      int run = carry;
#pragma unroll
      for (int w = 0; w < 16; ++w) { int t = wsum[w]; wsum[w] = run; run += t; }
      carry = run;
    }
    __syncthreads();
    if (idx <= n) row_ptr[idx] = wsum[wid] + x - v;
    __syncthreads();
  }
}

__global__ __launch_bounds__(256) void place_kernel(const int* __restrict__ src,
                                                    const int* __restrict__ dst,
                                                    const int* __restrict__ row_ptr,
                                                    int* __restrict__ cursor,
                                                    int* __restrict__ srcs, int E) {
  int e = blockIdx.x * 256 + threadIdx.x;
  if (e < E) {
    int d = dst[e];
    int pos = row_ptr[d] + atomicAdd(&cursor[d], 1);
    srcs[pos] = src[e];
  }
}

// ---------------- Conversions ----------------

__global__ __launch_bounds__(256) void cvt_bf16_kernel(const float* __restrict__ in,
                                                       short* __restrict__ out, int n4) {
  int i = blockIdx.x * 256 + threadIdx.x;
  if (i >= n4) return;
  float4 v = ((const float4*)in)[i];
  short4 o;
  o.x = f2bf(v.x); o.y = f2bf(v.y); o.z = f2bf(v.z); o.w = f2bf(v.w);
  ((short4*)out)[i] = o;
}

// W[K,N] f32 -> WT[N,K] bf16
__global__ __launch_bounds__(256) void cvt_wT_kernel(const float* __restrict__ W,
                                                     short* __restrict__ WT, int K, int N) {
  int i = blockIdx.x * 256 + threadIdx.x;
  if (i >= K * N) return;
  int k = i / N, n = i - k * N;
  WT[(size_t)n * K + k] = f2bf(W[i]);
}

// ---------------- bf16 MFMA GEMM: C[M,N] = A[M,K] @ BT[N,K]^T (+bias) -------
// 128x64 tile, BK=32, 4 waves in 2x2, each wave 4x2 MFMA 16x16x32 tiles.

__global__ __launch_bounds__(256) void bgemm_kernel(const short* __restrict__ A,
                                                    const short* __restrict__ BT,
                                                    const float* __restrict__ bias,
                                                    float* __restrict__ C,
                                                    int M, int N, int K) {
  __shared__ short As[128 * 32];  // 8 KB
  __shared__ short Bs[64 * 32];   // 4 KB
  const int tid = threadIdx.x;
  const int w = tid >> 6, lane = tid & 63;
  const int wM = w >> 1, wN = w & 1;
  const int rowBase = blockIdx.y * 128;
  const int colBase = blockIdx.x * 64;
  const int l15 = lane & 15, q = lane >> 4;

  f32x4 acc[4][2];
#pragma unroll
  for (int i = 0; i < 4; ++i)
#pragma unroll
    for (int j = 0; j < 2; ++j) acc[i][j] = (f32x4){0.f, 0.f, 0.f, 0.f};

  for (int k0 = 0; k0 < K; k0 += 32) {
    // A tile: 128 rows x 32 k = 512 chunks of 8 bf16 (16 B). Wave w: chunks
    // [w*128, w*128+128). LDS dest = wave-uniform base + lane*16 (HW rule).
#pragma unroll
    for (int i = 0; i < 2; ++i) {
      int c = w * 128 + i * 64 + lane;
      int m = c >> 2, qq = c & 3;
      int gm = rowBase + m; if (gm >= M) gm = M - 1;  // clamp; stores guarded
      async_cp16(A + (size_t)gm * K + k0 + qq * 8, &As[(w * 128 + i * 64) * 8]);
    }
    // B^T tile: 64 n-rows x 32 k = 256 chunks. Wave w: chunks [w*64, w*64+64).
    {
      int c = w * 64 + lane;
      int n = c >> 2, qq = c & 3;
      async_cp16(BT + (size_t)(colBase + n) * K + k0 + qq * 8, &Bs[(w * 64) * 8]);
    }
    __syncthreads();  // implies vmcnt(0): global_load_lds drained

    bf16x8 af[4], bfr[2];
#pragma unroll
    for (int tm = 0; tm < 4; ++tm)
      af[tm] = *(const bf16x8*)&As[(wM * 64 + tm * 16 + l15) * 32 + q * 8];
#pragma unroll
    for (int tn = 0; tn < 2; ++tn)
      bfr[tn] = *(const bf16x8*)&Bs[(wN * 32 + tn * 16 + l15) * 32 + q * 8];
#pragma unroll
    for (int tm = 0; tm < 4; ++tm)
#pragma unroll
      for (int tn = 0; tn < 2; ++tn)
        acc[tm][tn] = __builtin_amdgcn_mfma_f32_16x16x32_bf16(af[tm], bfr[tn],
                                                              acc[tm][tn], 0, 0, 0);
    __syncthreads();
  }

  // epilogue: D elem r at lane l -> row=(l>>4)*4+r, col=l&15 within 16x16 tile
#pragma unroll
  for (int tn = 0; tn < 2; ++tn) {
    int col = colBase + wN * 32 + tn * 16 + l15;
    float bv = bias ? bias[col] : 0.0f;
#pragma unroll
    for (int tm = 0; tm < 4; ++tm) {
      int r0 = rowBase + wM * 64 + tm * 16 + q * 4;
#pragma unroll
      for (int r = 0; r < 4; ++r) {
        int row = r0 + r;
        if (row < M) C[(size_t)row * N + col] = acc[tm][tn][r] + bv;
      }
    }
  }
}

// ---------------- Edge aggregation (one wave per node) ----------------

__global__ __launch_bounds__(256) void agg256_kernel(const float* __restrict__ h,
                                                     const float* __restrict__ dinv,
                                                     const int* __restrict__ row_ptr,
                                                     const int* __restrict__ srcs,
                                                     const float* __restrict__ bias,
                                                     float* __restrict__ out, int N) {
  int gw = (blockIdx.x * 256 + threadIdx.x) >> 6;
  int lane = threadIdx.x & 63;
  if (gw >= N) return;
  float dn = dinv[gw];
  int e0 = row_ptr[gw], e1 = row_ptr[gw + 1];
  const float4* h4 = (const float4*)h;
  float4 acc = make_float4(0.f, 0.f, 0.f, 0.f);
  for (int e = e0; e < e1; ++e) {
    int s = srcs[e];
    float w = dinv[s] * dn;
    float4 v = h4[(size_t)s * 64 + lane];
    acc.x += v.x * w; acc.y += v.y * w; acc.z += v.z * w; acc.w += v.w * w;
  }
  {
    float w = dn * dn;
    float4 v = h4[(size_t)gw * 64 + lane];
    acc.x += v.x * w; acc.y += v.y * w; acc.z += v.z * w; acc.w += v.w * w;
  }
  float4 b = ((const float4*)bias)[lane];
  acc.x += b.x; acc.y += b.y; acc.z += b.z; acc.w += b.w;
  ((float4*)out)[(size_t)gw * 64 + lane] = acc;
}

__global__ __launch_bounds__(256) void agg128_kernel(const float* __restrict__ h,
                                                     const float* __restrict__ dinv,
                                                     const int* __restrict__ row_ptr,
                                                     const int* __restrict__ srcs,
                                                     const float* __restrict__ bias,
                                                     float* __restrict__ out, int N) {
  int gw = (blockIdx.x * 256 + threadIdx.x) >> 6;
  int lane = threadIdx.x & 63;
  if (gw >= N) return;
  float dn = dinv[gw];
  int e0 = row_ptr[gw], e1 = row_ptr[gw + 1];
  const float2* h2 = (const float2*)h;
  float2 acc = make_float2(0.f, 0.f);
  for (int e = e0; e < e1; ++e) {
    int s = srcs[e];
    float w = dinv[s] * dn;
    float2 v = h2[(size_t)s * 64 + lane];
    acc.x += v.x * w; acc.y += v.y * w;
  }
  {
    float w = dn * dn;
    float2 v = h2[(size_t)gw * 64 + lane];
    acc.x += v.x * w; acc.y += v.y * w;
  }
  float2 b = ((const float2*)bias)[lane];
  acc.x += b.x; acc.y += b.y;
  ((float2*)out)[(size_t)gw * 64 + lane] = acc;
}

// ---------------- BatchNorm ----------------

__global__ __launch_bounds__(256) void bn_stats_kernel(const float* __restrict__ h,
                                                       float* __restrict__ sums, int N) {
  int c = threadIdx.x;
  int rows_per = (N + gridDim.x - 1) / gridDim.x;
  int r0 = blockIdx.x * rows_per;
  int r1 = min(N, r0 + rows_per);
  float s = 0.f, ss = 0.f;
  for (int r = r0; r < r1; ++r) {
    float v = h[(size_t)r * C_HID + c];
    s += v; ss += v * v;
  }
  atomicAdd(&sums[c], s);
  atomicAdd(&sums[C_HID + c], ss);
}

// normalize + gamma/beta + ReLU, write bf16 (input to GEMM2)
__global__ __launch_bounds__(256) void bn_apply_kernel(const float* __restrict__ h,
                                                       const float* __restrict__ sums,
                                                       const float* __restrict__ gamma,
                                                       const float* __restrict__ beta,
                                                       short* __restrict__ out_bf, int N) {
  int c = threadIdx.x;
  float invN = 1.0f / (float)N;
  float mu = sums[c] * invN;
  float var = sums[C_HID + c] * invN - mu * mu;
  float sc = gamma[c] * rsqrtf(var + 1e-5f);
  float sh = beta[c] - mu * sc;
  int rows_per = (N + gridDim.x - 1) / gridDim.x;
  int r0 = blockIdx.x * rows_per;
  int r1 = min(N, r0 + rows_per);
  for (int r = r0; r < r1; ++r) {
    size_t idx = (size_t)r * C_HID + c;
    out_bf[idx] = f2bf(fmaxf(h[idx] * sc + sh, 0.0f));
  }
}

// ---------------- LayerNorm + ReLU -> bf16 (input to GEMM3) ----------------

__global__ __launch_bounds__(256) void ln_relu_kernel(const float* __restrict__ h,
                                                      const float* __restrict__ gamma,
                                                      const float* __restrict__ beta,
                                                      short* __restrict__ out_bf, int N) {
  int gw = (blockIdx.x * 256 + threadIdx.x) >> 6;
  int lane = threadIdx.x & 63;
  if (gw >= N) return;
  const float2* h2 = (const float2*)h;
  float2 v = h2[(size_t)gw * 64 + lane];
  float s = v.x + v.y;
  float ss = v.x * v.x + v.y * v.y;
#pragma unroll
  for (int d = 1; d < 64; d <<= 1) {
    s += __shfl_xor(s, d, 64);
    ss += __shfl_xor(ss, d, 64);
  }
  float mu = s * (1.0f / C_OUT);
  float var = ss * (1.0f / C_OUT) - mu * mu;
  float rs = rsqrtf(var + 1e-5f);
  int c = lane * 2;
  float o0 = fmaxf((v.x - mu) * rs * gamma[c] + beta[c], 0.0f);
  float o1 = fmaxf((v.y - mu) * rs * gamma[c + 1] + beta[c + 1], 0.0f);
  ((short2*)out_bf)[(size_t)gw * 64 + lane] = make_short2(f2bf(o0), f2bf(o1));
}

// ---------------- Decode (one wave per pair) ----------------

__global__ __launch_bounds__(256) void decode_kernel(const float* __restrict__ z,
                                                     const int* __restrict__ eli,
                                                     const float* __restrict__ cutoff,
                                                     float* __restrict__ out, int EL) {
  int gw = (blockIdx.x * 256 + threadIdx.x) >> 6;
  int lane = threadIdx.x & 63;
  if (gw >= EL) return;
  int a = eli[gw];
  int b = eli[EL + gw];
  const float2* z2 = (const float2*)z;
  float2 va = z2[(size_t)a * 64 + lane];
  float2 vb = z2[(size_t)b * 64 + lane];
  float s = va.x * vb.x + va.y * vb.y;
#pragma unroll
  for (int d = 1; d < 64; d <<= 1) s += __shfl_xor(s, d, 64);
  if (lane == 0) {
    out[gw] = s;
    out[EL + gw] = (s < cutoff[0]) ? 0.0f : 1.0f;
  }
}

// ---------------- Launch ----------------

extern "C" void kernel_launch(void* const* d_in, const int* in_sizes, int n_in,
                              void* d_out, int out_size, void* d_ws, size_t ws_size,
                              hipStream_t stream) {
  const float* x        = (const float*)d_in[0];
  const int*   eidx     = (const int*)d_in[1];
  const int*   eli      = (const int*)d_in[2];
  const float* cutoff   = (const float*)d_in[3];
  const float* W1       = (const float*)d_in[4];
  const float* b1       = (const float*)d_in[5];
  const float* bn_gamma = (const float*)d_in[6];
  const float* bn_beta  = (const float*)d_in[7];
  const float* W2       = (const float*)d_in[8];
  const float* b2       = (const float*)d_in[9];
  const float* ln_gamma = (const float*)d_in[10];
  const float* ln_beta  = (const float*)d_in[11];
  const float* lin_W    = (const float*)d_in[12];
  const float* lin_b    = (const float*)d_in[13];
  float* out = (float*)d_out;

  const int N  = in_sizes[0] / C_IN;   // 100000
  const int E  = in_sizes[1] / 2;      // 800000
  const int EL = in_sizes[2] / 2;      // 200000

  const int* src = eidx;
  const int* dst = eidx + E;

  // workspace layout
  char* ws = (char*)d_ws;
  float* buf1 = (float*)ws;  ws += (size_t)N * C_HID * 4;
  float* buf2 = (float*)ws;  ws += (size_t)N * C_HID * 4;
  float* dinv = (float*)ws;  ws += (size_t)N * 4;
  int* counts = (int*)ws;    ws += (size_t)N * 4;
  int* row_ptr = (int*)ws;   ws += (size_t)(N + 4) * 4;
  int* cursor = (int*)ws;    ws += (size_t)N * 4;
  int* srcs = (int*)ws;      ws += (size_t)E * 4;
  float* sums = (float*)ws;  ws += 2 * C_HID * 4;
  short* w1t = (short*)ws;   ws += (size_t)C_HID * C_IN * 2;   // [256][128]
  short* w2t = (short*)ws;   ws += (size_t)C_OUT * C_HID * 2;  // [128][256]
  short* w3t = (short*)ws;   ws += (size_t)C_OUT * C_OUT * 2;  // [128][128]

  // bf16 activation overlays into dead halves of buf1/buf2:
  short* x_bf   = (short*)buf2;                      // dead before agg1 writes buf2
  short* h1n_bf = (short*)(buf1 + (size_t)N * 128);  // buf1 2nd half (h1 dead after agg1)
  short* z_bf   = (short*)(buf2 + (size_t)N * 128);  // buf2 2nd half (agg2 out is 128-wide)

  hipMemsetAsync(counts, 0, (size_t)N * 4, stream);
  hipMemsetAsync(sums, 0, 2 * C_HID * 4, stream);

  int eb = (E + 255) / 256;
  int nb = (N + 255) / 256;

  hist_kernel<<<eb, 256, 0, stream>>>(dst, counts, E);
  dinv_kernel<<<nb, 256, 0, stream>>>(counts, dinv, cursor, N);
  scan_kernel<<<1, 1024, 0, stream>>>(counts, row_ptr, N);
  place_kernel<<<eb, 256, 0, stream>>>(src, dst, row_ptr, cursor, srcs, E);

  // weight transpose+convert (tiny)
  cvt_wT_kernel<<<(C_IN * C_HID + 255) / 256, 256, 0, stream>>>(W1, w1t, C_IN, C_HID);
  cvt_wT_kernel<<<(C_HID * C_OUT + 255) / 256, 256, 0, stream>>>(W2, w2t, C_HID, C_OUT);
  cvt_wT_kernel<<<(C_OUT * C_OUT + 255) / 256, 256, 0, stream>>>(lin_W, w3t, C_OUT, C_OUT);

  // x -> bf16
  int xn4 = N * C_IN / 4;
  cvt_bf16_kernel<<<(xn4 + 255) / 256, 256, 0, stream>>>(x, x_bf, xn4);

  // GEMM1: h1 = x @ W1   [N x 256]
  dim3 g1(C_HID / 64, (N + 127) / 128);
  bgemm_kernel<<<g1, 256, 0, stream>>>(x_bf, w1t, nullptr, buf1, N, C_HID, C_IN);

  int wb = ((size_t)N * 64 + 255) / 256;
  agg256_kernel<<<wb, 256, 0, stream>>>(buf1, dinv, row_ptr, srcs, b1, buf2, N);

  bn_stats_kernel<<<512, 256, 0, stream>>>(buf2, sums, N);
  bn_apply_kernel<<<1024, 256, 0, stream>>>(buf2, sums, bn_gamma, bn_beta, h1n_bf, N);

  // GEMM2: h2 = h1n @ W2  [N x 128]
  dim3 g2(C_OUT / 64, (N + 127) / 128);
  bgemm_kernel<<<g2, 256, 0, stream>>>(h1n_bf, w2t, nullptr, buf1, N, C_OUT, C_HID);

  agg128_kernel<<<wb, 256, 0, stream>>>(buf1, dinv, row_ptr, srcs, b2, buf2, N);

  ln_relu_kernel<<<wb, 256, 0, stream>>>(buf2, ln_gamma, ln_beta, z_bf, N);

  // GEMM3: zlin = z @ lin_W + lin_b  [N x 128]
  dim3 g3(C_OUT / 64, (N + 127) / 128);
  bgemm_kernel<<<g3, 256, 0, stream>>>(z_bf, w3t, lin_b, buf1, N, C_OUT, C_OUT);

  int db = ((size_t)EL * 64 + 255) / 256;
  decode_kernel<<<db, 256, 0, stream>>>(buf1, eli, cutoff, out, EL);
}

// Round 3
// 704.572 us; speedup vs baseline: 1.4489x; 1.0699x over previous
//
#include <hip/hip_runtime.h>
#include <stdint.h>

// ---------------------------------------------------------------------------
// Net_60129542953 R3:
//  - Layer-1 aggregation commuted before GEMM (agg(x)@W1 == agg(x@W1)),
//    gathers run on bf16 rows (256 B instead of 1 KB).
//  - BN stats fused into GEMM1 epilogue; LN+ReLU fused into agg2 epilogue.
//  - Per-edge coef dinv[s]*dinv[d] precomputed in place_kernel.
//  - GEMM3 output + decode stay f32 (sign-threshold safety).
// ---------------------------------------------------------------------------

#define C_IN  128
#define C_HID 256
#define C_OUT 128

typedef __attribute__((ext_vector_type(8))) short bf16x8;
typedef __attribute__((ext_vector_type(4))) float f32x4;

__device__ __forceinline__ short f2bf(float f) {
  union { float f; uint32_t u; } v; v.f = f;
  uint32_t r = v.u + 0x7FFFu + ((v.u >> 16) & 1u);  // RNE
  return (short)(r >> 16);
}
__device__ __forceinline__ uint32_t pack_bf2(float a, float b) {
  return (uint32_t)(uint16_t)f2bf(a) | ((uint32_t)(uint16_t)f2bf(b) << 16);
}
__device__ __forceinline__ float bflo(uint32_t p) {
  union { uint32_t u; float f; } v; v.u = p << 16; return v.f;
}
__device__ __forceinline__ float bfhi(uint32_t p) {
  union { uint32_t u; float f; } v; v.u = p & 0xffff0000u; return v.f;
}

__device__ __forceinline__ void async_cp16(const void* g, void* l) {
  __builtin_amdgcn_global_load_lds((const __attribute__((address_space(1))) void*)g,
                                   (__attribute__((address_space(3))) void*)l, 16, 0, 0);
}

// ---------------- CSR build ----------------

__global__ __launch_bounds__(256) void hist_kernel(const int* __restrict__ dst,
                                                   int* __restrict__ counts, int E) {
  int e = blockIdx.x * 256 + threadIdx.x;
  if (e < E) atomicAdd(&counts[dst[e]], 1);
}

__global__ __launch_bounds__(256) void dinv_kernel(const int* __restrict__ counts,
                                                   float* __restrict__ dinv,
                                                   int* __restrict__ cursor, int N) {
  int n = blockIdx.x * 256 + threadIdx.x;
  if (n < N) {
    dinv[n] = rsqrtf((float)counts[n] + 1.0f);  // deg = indeg + 1 (self loop)
    cursor[n] = 0;
  }
}

__global__ __launch_bounds__(1024) void scan_kernel(const int* __restrict__ counts,
                                                    int* __restrict__ row_ptr, int n) {
  __shared__ int wsum[16];
  int tid = threadIdx.x;
  int lane = tid & 63, wid = tid >> 6;
  int carry = 0;
  for (int base = 0; base <= n; base += 1024) {
    int idx = base + tid;
    int v = (idx < n) ? counts[idx] : 0;
    int x = v;
#pragma unroll
    for (int d = 1; d < 64; d <<= 1) {
      int y = __shfl_up(x, d, 64);
      if (lane >= d) x += y;
    }
    if (lane == 63) wsum[wid] = x;
    __syncthreads();
    if (tid == 0) {
      int run = carry;
#pragma unroll
      for (int w = 0; w < 16; ++w) { int t = wsum[w]; wsum[w] = run; run += t; }
      carry = run;
    }
    __syncthreads();
    if (idx <= n) row_ptr[idx] = wsum[wid] + x - v;
    __syncthreads();
  }
}

// edges[pos] = {src, dinv[src]*dinv[dst]}
__global__ __launch_bounds__(256) void place_kernel(const int* __restrict__ src,
                                                    const int* __restrict__ dst,
                                                    const int* __restrict__ row_ptr,
                                                    int* __restrict__ cursor,
                                                    const float* __restrict__ dinv,
                                                    int2* __restrict__ edges, int E) {
  int e = blockIdx.x * 256 + threadIdx.x;
  if (e < E) {
    int d = dst[e], s = src[e];
    int pos = row_ptr[d] + atomicAdd(&cursor[d], 1);
    int2 ed; ed.x = s; ed.y = __float_as_int(dinv[s] * dinv[d]);
    edges[pos] = ed;
  }
}

// ---------------- Conversions ----------------

__global__ __launch_bounds__(256) void cvt_bf16_kernel(const float* __restrict__ in,
                                                       short* __restrict__ out, int n4) {
  int i = blockIdx.x * 256 + threadIdx.x;
  if (i >= n4) return;
  float4 v = ((const float4*)in)[i];
  short4 o;
  o.x = f2bf(v.x); o.y = f2bf(v.y); o.z = f2bf(v.z); o.w = f2bf(v.w);
  ((short4*)out)[i] = o;
}

// W[K,N] f32 -> WT[N,K] bf16
__global__ __launch_bounds__(256) void cvt_wT_kernel(const float* __restrict__ W,
                                                     short* __restrict__ WT, int K, int N) {
  int i = blockIdx.x * 256 + threadIdx.x;
  if (i >= K * N) return;
  int k = i / N, n = i - k * N;
  WT[(size_t)n * K + k] = f2bf(W[i]);
}

// ---------------- bf16 MFMA GEMM: C[M,N] = A[M,K] @ BT[N,K]^T (+bias) -------
// 128x128 tile, BK=32, 4 waves 2x2, each wave 64x64 (4x4 MFMA 16x16x32).
// MODE 0: f32 out; 1: bf16 out; 2: bf16 out + fused BN partial stats.

template <int MODE>
__global__ __launch_bounds__(256) void bgemm128_kernel(const short* __restrict__ A,
                                                       const short* __restrict__ BT,
                                                       const float* __restrict__ bias,
                                                       void* __restrict__ Cout,
                                                       float* __restrict__ sums,
                                                       int M, int N, int K) {
  __shared__ short As[128 * 32];  // 8 KB
  __shared__ short Bs[128 * 32];  // 8 KB
  const int tid = threadIdx.x;
  const int w = tid >> 6, lane = tid & 63;
  const int wM = w >> 1, wN = w & 1;
  const int rowBase = blockIdx.y * 128;
  const int colBase = blockIdx.x * 128;
  const int l15 = lane & 15, q = lane >> 4;

  f32x4 acc[4][4];
#pragma unroll
  for (int i = 0; i < 4; ++i)
#pragma unroll
    for (int j = 0; j < 4; ++j) acc[i][j] = (f32x4){0.f, 0.f, 0.f, 0.f};

  for (int k0 = 0; k0 < K; k0 += 32) {
#pragma unroll
    for (int i = 0; i < 2; ++i) {
      int c = w * 128 + i * 64 + lane;
      int m = c >> 2, kq = c & 3;
      int gm = rowBase + m; if (gm >= M) gm = M - 1;  // clamp; guarded later
      async_cp16(A + (size_t)gm * K + k0 + kq * 8, &As[(w * 128 + i * 64) * 8]);
      async_cp16(BT + (size_t)(colBase + m) * K + k0 + kq * 8,
                 &Bs[(w * 128 + i * 64) * 8]);
    }
    __syncthreads();

    bf16x8 af[4], bfr[4];
#pragma unroll
    for (int tm = 0; tm < 4; ++tm)
      af[tm] = *(const bf16x8*)&As[(wM * 64 + tm * 16 + l15) * 32 + q * 8];
#pragma unroll
    for (int tn = 0; tn < 4; ++tn)
      bfr[tn] = *(const bf16x8*)&Bs[(wN * 64 + tn * 16 + l15) * 32 + q * 8];
#pragma unroll
    for (int tm = 0; tm < 4; ++tm)
#pragma unroll
      for (int tn = 0; tn < 4; ++tn)
        acc[tm][tn] = __builtin_amdgcn_mfma_f32_16x16x32_bf16(af[tm], bfr[tn],
                                                              acc[tm][tn], 0, 0, 0);
    __syncthreads();
  }

  // D elem r at lane l -> row = (l>>4)*4 + r, col = l&15 within a 16x16 tile
#pragma unroll
  for (int tn = 0; tn < 4; ++tn) {
    int col = colBase + wN * 64 + tn * 16 + l15;
    float bv = bias ? bias[col] : 0.0f;
    float s = 0.f, ss = 0.f;
#pragma unroll
    for (int tm = 0; tm < 4; ++tm) {
      int r0 = rowBase + wM * 64 + tm * 16 + q * 4;
#pragma unroll
      for (int r = 0; r < 4; ++r) {
        int row = r0 + r;
        if (row < M) {
          float v = acc[tm][tn][r] + bv;
          if (MODE == 0) ((float*)Cout)[(size_t)row * N + col] = v;
          else           ((short*)Cout)[(size_t)row * N + col] = f2bf(v);
          if (MODE == 2) { s += v; ss += v * v; }
        }
      }
    }
    if (MODE == 2) {
      s += __shfl_xor(s, 16); s += __shfl_xor(s, 32);
      ss += __shfl_xor(ss, 16); ss += __shfl_xor(ss, 32);
      if (q == 0) {
        atomicAdd(&sums[col], s);
        atomicAdd(&sums[N + col], ss);
      }
    }
  }
}

// ---------------- Aggregations (one wave per node, bf16 rows of 128) --------

// xa[n] = sum_e coef_e * x[src_e] + dinv[n]^2 * x[n]   (bf16 in, bf16 out)
__global__ __launch_bounds__(256) void agg_x_kernel(const uint32_t* __restrict__ xb,
                                                    const float* __restrict__ dinv,
                                                    const int* __restrict__ row_ptr,
                                                    const int2* __restrict__ edges,
                                                    uint32_t* __restrict__ outb, int N) {
  int gw = (blockIdx.x * 256 + threadIdx.x) >> 6;
  int lane = threadIdx.x & 63;
  if (gw >= N) return;
  int e0 = row_ptr[gw], e1 = row_ptr[gw + 1];
  float a0 = 0.f, a1 = 0.f;
  for (int e = e0; e < e1; ++e) {
    int2 ed = edges[e];
    float wt = __int_as_float(ed.y);
    uint32_t p = xb[(size_t)ed.x * 64 + lane];
    a0 += bflo(p) * wt; a1 += bfhi(p) * wt;
  }
  float dn = dinv[gw], ws = dn * dn;
  uint32_t p = xb[(size_t)gw * 64 + lane];
  a0 += bflo(p) * ws; a1 += bfhi(p) * ws;
  outb[(size_t)gw * 64 + lane] = pack_bf2(a0, a1);
}

// z[n] = relu(LN(agg(h2)[n] + b2)) in bf16  (fused conv2-agg + bias + LN + ReLU)
__global__ __launch_bounds__(256) void agg_ln_kernel(const uint32_t* __restrict__ hb,
                                                     const float* __restrict__ dinv,
                                                     const int* __restrict__ row_ptr,
                                                     const int2* __restrict__ edges,
                                                     const float* __restrict__ bias,
                                                     const float* __restrict__ gamma,
                                                     const float* __restrict__ beta,
                                                     uint32_t* __restrict__ zb, int N) {
  int gw = (blockIdx.x * 256 + threadIdx.x) >> 6;
  int lane = threadIdx.x & 63;
  if (gw >= N) return;
  int e0 = row_ptr[gw], e1 = row_ptr[gw + 1];
  float a0 = 0.f, a1 = 0.f;
  for (int e = e0; e < e1; ++e) {
    int2 ed = edges[e];
    float wt = __int_as_float(ed.y);
    uint32_t p = hb[(size_t)ed.x * 64 + lane];
    a0 += bflo(p) * wt; a1 += bfhi(p) * wt;
  }
  float dn = dinv[gw], ws = dn * dn;
  uint32_t p = hb[(size_t)gw * 64 + lane];
  a0 += bflo(p) * ws; a1 += bfhi(p) * ws;
  int c = lane * 2;
  a0 += bias[c]; a1 += bias[c + 1];
  float s = a0 + a1, ss = a0 * a0 + a1 * a1;
#pragma unroll
  for (int d = 1; d < 64; d <<= 1) {
    s += __shfl_xor(s, d);
    ss += __shfl_xor(ss, d);
  }
  float mu = s * (1.0f / C_OUT);
  float var = ss * (1.0f / C_OUT) - mu * mu;
  float rs = rsqrtf(var + 1e-5f);
  float o0 = fmaxf((a0 - mu) * rs * gamma[c] + beta[c], 0.0f);
  float o1 = fmaxf((a1 - mu) * rs * gamma[c + 1] + beta[c + 1], 0.0f);
  zb[(size_t)gw * 64 + lane] = pack_bf2(o0, o1);
}

// ---------------- BatchNorm apply (bf16 h1 -> bf16 relu'd h1n) ----------------

__global__ __launch_bounds__(256) void bn_apply_kernel(const uint32_t* __restrict__ hb,
                                                       const float* __restrict__ sums,
                                                       const float* __restrict__ gamma,
                                                       const float* __restrict__ beta,
                                                       uint32_t* __restrict__ ob,
                                                       int total, float invN) {
  int i = blockIdx.x * 256 + threadIdx.x;
  if (i >= total) return;
  int c = (i & 127) * 2;  // 128 uints per row of 256 channels
  float mu0 = sums[c] * invN, mu1 = sums[c + 1] * invN;
  float v0 = sums[C_HID + c] * invN - mu0 * mu0;
  float v1 = sums[C_HID + c + 1] * invN - mu1 * mu1;
  float sc0 = gamma[c] * rsqrtf(v0 + 1e-5f);
  float sc1 = gamma[c + 1] * rsqrtf(v1 + 1e-5f);
  float sh0 = beta[c] - mu0 * sc0;
  float sh1 = beta[c + 1] - mu1 * sc1;
  uint32_t p = hb[i];
  float o0 = fmaxf(bflo(p) * sc0 + sh0, 0.0f);
  float o1 = fmaxf(bfhi(p) * sc1 + sh1, 0.0f);
  ob[i] = pack_bf2(o0, o1);
}

// ---------------- Decode (one wave per pair, f32 z) ----------------

__global__ __launch_bounds__(256) void decode_kernel(const float* __restrict__ z,
                                                     const int* __restrict__ eli,
                                                     const float* __restrict__ cutoff,
                                                     float* __restrict__ out, int EL) {
  int gw = (blockIdx.x * 256 + threadIdx.x) >> 6;
  int lane = threadIdx.x & 63;
  if (gw >= EL) return;
  int a = eli[gw];
  int b = eli[EL + gw];
  const float2* z2 = (const float2*)z;
  float2 va = z2[(size_t)a * 64 + lane];
  float2 vb = z2[(size_t)b * 64 + lane];
  float s = va.x * vb.x + va.y * vb.y;
#pragma unroll
  for (int d = 1; d < 64; d <<= 1) s += __shfl_xor(s, d);
  if (lane == 0) {
    out[gw] = s;
    out[EL + gw] = (s < cutoff[0]) ? 0.0f : 1.0f;
  }
}

// ---------------- Launch ----------------

extern "C" void kernel_launch(void* const* d_in, const int* in_sizes, int n_in,
                              void* d_out, int out_size, void* d_ws, size_t ws_size,
                              hipStream_t stream) {
  const float* x        = (const float*)d_in[0];
  const int*   eidx     = (const int*)d_in[1];
  const int*   eli      = (const int*)d_in[2];
  const float* cutoff   = (const float*)d_in[3];
  const float* W1       = (const float*)d_in[4];
  const float* b1       = (const float*)d_in[5];
  const float* bn_gamma = (const float*)d_in[6];
  const float* bn_beta  = (const float*)d_in[7];
  const float* W2       = (const float*)d_in[8];
  const float* b2       = (const float*)d_in[9];
  const float* ln_gamma = (const float*)d_in[10];
  const float* ln_beta  = (const float*)d_in[11];
  const float* lin_W    = (const float*)d_in[12];
  const float* lin_b    = (const float*)d_in[13];
  float* out = (float*)d_out;

  const int N  = in_sizes[0] / C_IN;   // 100000
  const int E  = in_sizes[1] / 2;      // 800000
  const int EL = in_sizes[2] / 2;      // 200000

  const int* src = eidx;
  const int* dst = eidx + E;

  // workspace layout (regions reused across phases)
  char* p = (char*)d_ws;
  short* regionA = (short*)p;  p += (size_t)N * 256 * 2;  // x_bf+xa_bf, later h1n_bf
  short* regionB = (short*)p;  p += (size_t)N * 256 * 2;  // h1_bf, later z_bf
  short* h2_bf   = (short*)p;  p += (size_t)N * 128 * 2;
  float* zfin    = (float*)p;  p += (size_t)N * 128 * 4;
  float* dinv    = (float*)p;  p += (size_t)N * 4;
  int* counts    = (int*)p;    p += (size_t)N * 4;
  int* row_ptr   = (int*)p;    p += (size_t)(N + 4) * 4;
  int* cursor    = (int*)p;    p += (size_t)N * 4;
  int2* edges    = (int2*)p;   p += (size_t)E * 8;
  float* sums    = (float*)p;  p += 2 * C_HID * 4;
  short* w1t     = (short*)p;  p += (size_t)C_HID * C_IN * 2;
  short* w2t     = (short*)p;  p += (size_t)C_OUT * C_HID * 2;
  short* w3t     = (short*)p;  p += (size_t)C_OUT * C_OUT * 2;

  short* x_bf   = regionA;                      // [N][128]
  short* xa_bf  = regionA + (size_t)N * 128;    // [N][128]
  short* h1_bf  = regionB;                      // [N][256]
  short* h1n_bf = regionA;                      // [N][256] (x/xa dead)
  short* z_bf   = regionB;                      // [N][128] (h1 dead)

  hipMemsetAsync(counts, 0, (size_t)N * 4, stream);
  hipMemsetAsync(sums, 0, 2 * C_HID * 4, stream);

  int eb = (E + 255) / 256;
  int nb = (N + 255) / 256;

  hist_kernel<<<eb, 256, 0, stream>>>(dst, counts, E);
  dinv_kernel<<<nb, 256, 0, stream>>>(counts, dinv, cursor, N);
  scan_kernel<<<1, 1024, 0, stream>>>(counts, row_ptr, N);
  place_kernel<<<eb, 256, 0, stream>>>(src, dst, row_ptr, cursor, dinv, edges, E);

  cvt_wT_kernel<<<(C_IN * C_HID + 255) / 256, 256, 0, stream>>>(W1, w1t, C_IN, C_HID);
  cvt_wT_kernel<<<(C_HID * C_OUT + 255) / 256, 256, 0, stream>>>(W2, w2t, C_HID, C_OUT);
  cvt_wT_kernel<<<(C_OUT * C_OUT + 255) / 256, 256, 0, stream>>>(lin_W, w3t, C_OUT, C_OUT);

  int xn4 = N * C_IN / 4;
  cvt_bf16_kernel<<<(xn4 + 255) / 256, 256, 0, stream>>>(x, x_bf, xn4);

  int wb = ((size_t)N * 64 + 255) / 256;  // one wave per node
  agg_x_kernel<<<wb, 256, 0, stream>>>((const uint32_t*)x_bf, dinv, row_ptr, edges,
                                       (uint32_t*)xa_bf, N);

  // GEMM1: h1 = agg(x) @ W1 + b1  [N x 256] bf16, fused BN partial stats
  dim3 g1(C_HID / 128, (N + 127) / 128);
  bgemm128_kernel<2><<<g1, 256, 0, stream>>>(xa_bf, w1t, b1, h1_bf, sums, N, C_HID, C_IN);

  int bnb = ((size_t)N * 128 + 255) / 256;
  bn_apply_kernel<<<bnb, 256, 0, stream>>>((const uint32_t*)h1_bf, sums, bn_gamma,
                                           bn_beta, (uint32_t*)h1n_bf, N * 128,
                                           1.0f / (float)N);

  // GEMM2: h2raw = h1n @ W2  [N x 128] bf16 (bias b2 added in agg_ln)
  dim3 g2(C_OUT / 128, (N + 127) / 128);
  bgemm128_kernel<1><<<g2, 256, 0, stream>>>(h1n_bf, w2t, nullptr, h2_bf, nullptr,
                                             N, C_OUT, C_HID);

  agg_ln_kernel<<<wb, 256, 0, stream>>>((const uint32_t*)h2_bf, dinv, row_ptr, edges,
                                        b2, ln_gamma, ln_beta, (uint32_t*)z_bf, N);

  // GEMM3: zfin = z @ lin_W + lin_b  [N x 128] f32
  dim3 g3(C_OUT / 128, (N + 127) / 128);
  bgemm128_kernel<0><<<g3, 256, 0, stream>>>(z_bf, w3t, lin_b, zfin, nullptr,
                                             N, C_OUT, C_OUT);

  int db = ((size_t)EL * 64 + 255) / 256;
  decode_kernel<<<db, 256, 0, stream>>>(zfin, eli, cutoff, out, EL);
}

// Round 4
// 621.689 us; speedup vs baseline: 1.6421x; 1.1333x over previous
//
#include <hip/hip_runtime.h>
#include <stdint.h>

// ---------------------------------------------------------------------------
// Net_60129542953 R4:
//  - bgemm_big: 128x128 tile, BK=128 (1 LDS drain per 64 MFMAs), XOR-swizzled
//    LDS (conflict-free fragment reads), LDS-staged coalesced C stores.
//  - BN stats via non-atomic per-block partials + 2-stage tree reduce
//    (R3's fused atomicAdd chains were the 102us GEMM1 bottleneck).
// ---------------------------------------------------------------------------

#define C_IN  128
#define C_HID 256
#define C_OUT 128

typedef __attribute__((ext_vector_type(8))) short bf16x8;
typedef __attribute__((ext_vector_type(4))) float f32x4;

__device__ __forceinline__ short f2bf(float f) {
  union { float f; uint32_t u; } v; v.f = f;
  uint32_t r = v.u + 0x7FFFu + ((v.u >> 16) & 1u);  // RNE
  return (short)(r >> 16);
}
__device__ __forceinline__ uint32_t pack_bf2(float a, float b) {
  return (uint32_t)(uint16_t)f2bf(a) | ((uint32_t)(uint16_t)f2bf(b) << 16);
}
__device__ __forceinline__ float bflo(uint32_t p) {
  union { uint32_t u; float f; } v; v.u = p << 16; return v.f;
}
__device__ __forceinline__ float bfhi(uint32_t p) {
  union { uint32_t u; float f; } v; v.u = p & 0xffff0000u; return v.f;
}

__device__ __forceinline__ void async_cp16(const void* g, void* l) {
  __builtin_amdgcn_global_load_lds((const __attribute__((address_space(1))) void*)g,
                                   (__attribute__((address_space(3))) void*)l, 16, 0, 0);
}

// ---------------- CSR build ----------------

__global__ __launch_bounds__(256) void hist_kernel(const int* __restrict__ dst,
                                                   int* __restrict__ counts, int E) {
  int e = blockIdx.x * 256 + threadIdx.x;
  if (e < E) atomicAdd(&counts[dst[e]], 1);
}

__global__ __launch_bounds__(256) void dinv_kernel(const int* __restrict__ counts,
                                                   float* __restrict__ dinv,
                                                   int* __restrict__ cursor, int N) {
  int n = blockIdx.x * 256 + threadIdx.x;
  if (n < N) {
    dinv[n] = rsqrtf((float)counts[n] + 1.0f);  // deg = indeg + 1 (self loop)
    cursor[n] = 0;
  }
}

__global__ __launch_bounds__(1024) void scan_kernel(const int* __restrict__ counts,
                                                    int* __restrict__ row_ptr, int n) {
  __shared__ int wsum[16];
  int tid = threadIdx.x;
  int lane = tid & 63, wid = tid >> 6;
  int carry = 0;
  for (int base = 0; base <= n; base += 1024) {
    int idx = base + tid;
    int v = (idx < n) ? counts[idx] : 0;
    int x = v;
#pragma unroll
    for (int d = 1; d < 64; d <<= 1) {
      int y = __shfl_up(x, d, 64);
      if (lane >= d) x += y;
    }
    if (lane == 63) wsum[wid] = x;
    __syncthreads();
    if (tid == 0) {
      int run = carry;
#pragma unroll
      for (int w = 0; w < 16; ++w) { int t = wsum[w]; wsum[w] = run; run += t; }
      carry = run;
    }
    __syncthreads();
    if (idx <= n) row_ptr[idx] = wsum[wid] + x - v;
    __syncthreads();
  }
}

// edges[pos] = {src, dinv[src]*dinv[dst]}
__global__ __launch_bounds__(256) void place_kernel(const int* __restrict__ src,
                                                    const int* __restrict__ dst,
                                                    const int* __restrict__ row_ptr,
                                                    int* __restrict__ cursor,
                                                    const float* __restrict__ dinv,
                                                    int2* __restrict__ edges, int E) {
  int e = blockIdx.x * 256 + threadIdx.x;
  if (e < E) {
    int d = dst[e], s = src[e];
    int pos = row_ptr[d] + atomicAdd(&cursor[d], 1);
    int2 ed; ed.x = s; ed.y = __float_as_int(dinv[s] * dinv[d]);
    edges[pos] = ed;
  }
}

// ---------------- Conversions ----------------

__global__ __launch_bounds__(256) void cvt_bf16_kernel(const float* __restrict__ in,
                                                       short* __restrict__ out, int n4) {
  int i = blockIdx.x * 256 + threadIdx.x;
  if (i >= n4) return;
  float4 v = ((const float4*)in)[i];
  short4 o;
  o.x = f2bf(v.x); o.y = f2bf(v.y); o.z = f2bf(v.z); o.w = f2bf(v.w);
  ((short4*)out)[i] = o;
}

// W[K,N] f32 -> WT[N,K] bf16
__global__ __launch_bounds__(256) void cvt_wT_kernel(const float* __restrict__ W,
                                                     short* __restrict__ WT, int K, int N) {
  int i = blockIdx.x * 256 + threadIdx.x;
  if (i >= K * N) return;
  int k = i / N, n = i - k * N;
  WT[(size_t)n * K + k] = f2bf(W[i]);
}

// ---------------- bf16 MFMA GEMM: C[M,N] = A[M,K] @ BT[N,K]^T (+bias) -------
// 128x128 tile, BK=128 (one LDS drain per chunk), 4 waves 2x2, wave = 64x64.
// LDS 64 KB: As/Bs 128x128 bf16 each, XOR-swizzled 16B chunks (kc ^= row&15)
// so fragment ds_read_b128 is 2-way max (free).
// MODE 0: f32 out; 1: bf16 out; 2: bf16 out + non-atomic BN partials.

template <int MODE>
__global__ __launch_bounds__(256, 2) void bgemm_big(const short* __restrict__ A,
                                                    const short* __restrict__ BT,
                                                    const float* __restrict__ bias,
                                                    void* __restrict__ Cout,
                                                    float* __restrict__ pS,
                                                    float* __restrict__ pSS,
                                                    int M, int N, int K) {
  __shared__ short smem[2 * 128 * 128];  // 64 KB
  short* As = smem;
  short* Bs = smem + 128 * 128;
  const int tid = threadIdx.x;
  const int w = tid >> 6, lane = tid & 63;
  const int wM = w >> 1, wN = w & 1;
  const int rowBase = blockIdx.y * 128;
  const int colBase = blockIdx.x * 128;
  const int l15 = lane & 15, q = lane >> 4;

  f32x4 acc[4][4];
#pragma unroll
  for (int i = 0; i < 4; ++i)
#pragma unroll
    for (int j = 0; j < 4; ++j) acc[i][j] = (f32x4){0.f, 0.f, 0.f, 0.f};

  for (int k0 = 0; k0 < K; k0 += 128) {
    // stage A: 128 rows x 128 k bf16 = 2048 16B chunks; physical slot p holds
    // global chunk (row=p>>4, kc=(p&15)^(row&15))
#pragma unroll
    for (int it = 0; it < 8; ++it) {
      int p = it * 256 + tid;
      int row = p >> 4, kcp = p & 15;
      int kc = kcp ^ (row & 15);
      int gm = rowBase + row; if (gm >= M) gm = M - 1;  // clamp; stores guarded
      async_cp16(A + (size_t)gm * K + k0 + kc * 8, &As[(it * 256 + w * 64) * 8]);
    }
#pragma unroll
    for (int it = 0; it < 8; ++it) {
      int p = it * 256 + tid;
      int row = p >> 4, kcp = p & 15;
      int kc = kcp ^ (row & 15);
      async_cp16(BT + (size_t)(colBase + row) * K + k0 + kc * 8,
                 &Bs[(it * 256 + w * 64) * 8]);
    }
    __syncthreads();  // single drain for the whole 64 KB stage

#pragma unroll
    for (int ks = 0; ks < 4; ++ks) {
      bf16x8 af[4], bfr[4];
#pragma unroll
      for (int tm = 0; tm < 4; ++tm) {
        int row = wM * 64 + tm * 16 + l15;
        int kcp = (ks * 4 + q) ^ l15;  // row&15 == l15
        af[tm] = *(const bf16x8*)&As[(row * 16 + kcp) * 8];
      }
#pragma unroll
      for (int tn = 0; tn < 4; ++tn) {
        int row = wN * 64 + tn * 16 + l15;
        int kcp = (ks * 4 + q) ^ l15;
        bfr[tn] = *(const bf16x8*)&Bs[(row * 16 + kcp) * 8];
      }
#pragma unroll
      for (int tm = 0; tm < 4; ++tm)
#pragma unroll
        for (int tn = 0; tn < 4; ++tn)
          acc[tm][tn] = __builtin_amdgcn_mfma_f32_16x16x32_bf16(af[tm], bfr[tn],
                                                                acc[tm][tn], 0, 0, 0);
    }
    __syncthreads();  // LDS reuse (next chunk / epilogue staging)
  }

  // ---- epilogue ----
  // D layout: elem r of lane l -> row=(l>>4)*4+r, col=l&15 in each 16x16 tile.
  if (MODE == 2) {
    // non-atomic BN partials: per (rowblock, wM) per col
#pragma unroll
    for (int tn = 0; tn < 4; ++tn) {
      int col = colBase + wN * 64 + tn * 16 + l15;
      float bv = bias ? bias[col] : 0.0f;
      float s = 0.f, ss = 0.f;
#pragma unroll
      for (int tm = 0; tm < 4; ++tm) {
        int r0 = rowBase + wM * 64 + tm * 16 + q * 4;
#pragma unroll
        for (int r = 0; r < 4; ++r) {
          if (r0 + r < M) { float v = acc[tm][tn][r] + bv; s += v; ss += v * v; }
        }
      }
      s += __shfl_xor(s, 16); s += __shfl_xor(s, 32);
      ss += __shfl_xor(ss, 16); ss += __shfl_xor(ss, 32);
      if (q == 0) {
        int prow = blockIdx.y * 2 + wM;
        pS[(size_t)prow * C_HID + col] = s;
        pSS[(size_t)prow * C_HID + col] = ss;
      }
    }
  }

  if (MODE == 0) {
    // stage f32 tile (64 KB exactly) then coalesced dwordx4 stores
    float* S = (float*)smem;
#pragma unroll
    for (int tn = 0; tn < 4; ++tn) {
      int col = wN * 64 + tn * 16 + l15;
      float bv = bias ? bias[colBase + col] : 0.0f;
#pragma unroll
      for (int tm = 0; tm < 4; ++tm) {
        int r0 = wM * 64 + tm * 16 + q * 4;
#pragma unroll
        for (int r = 0; r < 4; ++r) S[(r0 + r) * 128 + col] = acc[tm][tn][r] + bv;
      }
    }
    __syncthreads();
    float* Cf = (float*)Cout;
#pragma unroll
    for (int it = 0; it < 16; ++it) {
      int p = it * 256 + tid;
      int row = p >> 5, c = p & 31;
      int gm = rowBase + row;
      if (gm < M)
        *(uint4*)&Cf[(size_t)gm * N + colBase + c * 4] = ((const uint4*)S)[p];
    }
  } else {
    // stage bf16 tile (32 KB) then coalesced dwordx4 stores
    short* S = As;
#pragma unroll
    for (int tn = 0; tn < 4; ++tn) {
      int col = wN * 64 + tn * 16 + l15;
      float bv = bias ? bias[colBase + col] : 0.0f;
#pragma unroll
      for (int tm = 0; tm < 4; ++tm) {
        int r0 = wM * 64 + tm * 16 + q * 4;
#pragma unroll
        for (int r = 0; r < 4; ++r) S[(r0 + r) * 128 + col] = f2bf(acc[tm][tn][r] + bv);
      }
    }
    __syncthreads();
    short* Cb = (short*)Cout;
#pragma unroll
    for (int it = 0; it < 8; ++it) {
      int p = it * 256 + tid;
      int row = p >> 4, c = p & 15;
      int gm = rowBase + row;
      if (gm < M)
        *(uint4*)&Cb[(size_t)gm * N + colBase + c * 8] = ((const uint4*)S)[p];
    }
  }
}

// ---------------- BN stats tree reduce ----------------

// stage 1: 32 blocks, each sums a slice of the R partial rows
__global__ __launch_bounds__(256) void bn_red1_kernel(const float* __restrict__ pS,
                                                      const float* __restrict__ pSS,
                                                      float* __restrict__ oS,
                                                      float* __restrict__ oSS, int R) {
  int c = threadIdx.x;
  int per = (R + gridDim.x - 1) / gridDim.x;
  int r0 = blockIdx.x * per, r1 = min(R, r0 + per);
  float s = 0.f, ss = 0.f;
  for (int r = r0; r < r1; ++r) {
    s += pS[(size_t)r * C_HID + c];
    ss += pSS[(size_t)r * C_HID + c];
  }
  oS[(size_t)blockIdx.x * C_HID + c] = s;
  oSS[(size_t)blockIdx.x * C_HID + c] = ss;
}

// stage 2: 1 block of 256, produce scale/shift
__global__ __launch_bounds__(256) void bn_red2_kernel(const float* __restrict__ oS,
                                                      const float* __restrict__ oSS,
                                                      const float* __restrict__ gamma,
                                                      const float* __restrict__ beta,
                                                      float* __restrict__ bnp,
                                                      int G, float invN) {
  int c = threadIdx.x;
  float s = 0.f, ss = 0.f;
  for (int g = 0; g < G; ++g) {
    s += oS[(size_t)g * C_HID + c];
    ss += oSS[(size_t)g * C_HID + c];
  }
  float mu = s * invN;
  float var = ss * invN - mu * mu;
  float sc = gamma[c] * rsqrtf(var + 1e-5f);
  bnp[c] = sc;
  bnp[C_HID + c] = beta[c] - mu * sc;
}

// ---------------- BatchNorm apply (bf16 -> bf16 relu'd) ----------------

__global__ __launch_bounds__(256) void bn_apply_kernel(const uint32_t* __restrict__ hb,
                                                       const float* __restrict__ bnp,
                                                       uint32_t* __restrict__ ob,
                                                       int total) {
  int i = blockIdx.x * 256 + threadIdx.x;
  if (i >= total) return;
  int c = (i & 127) * 2;  // 128 uints per 256-channel row
  float sc0 = bnp[c], sc1 = bnp[c + 1];
  float sh0 = bnp[C_HID + c], sh1 = bnp[C_HID + c + 1];
  uint32_t p = hb[i];
  float o0 = fmaxf(bflo(p) * sc0 + sh0, 0.0f);
  float o1 = fmaxf(bfhi(p) * sc1 + sh1, 0.0f);
  ob[i] = pack_bf2(o0, o1);
}

// ---------------- Aggregations (one wave per node, bf16 rows of 128) --------

__global__ __launch_bounds__(256) void agg_x_kernel(const uint32_t* __restrict__ xb,
                                                    const float* __restrict__ dinv,
                                                    const int* __restrict__ row_ptr,
                                                    const int2* __restrict__ edges,
                                                    uint32_t* __restrict__ outb, int N) {
  int gw = (blockIdx.x * 256 + threadIdx.x) >> 6;
  int lane = threadIdx.x & 63;
  if (gw >= N) return;
  int e0 = row_ptr[gw], e1 = row_ptr[gw + 1];
  float a0 = 0.f, a1 = 0.f;
  for (int e = e0; e < e1; ++e) {
    int2 ed = edges[e];
    float wt = __int_as_float(ed.y);
    uint32_t p = xb[(size_t)ed.x * 64 + lane];
    a0 += bflo(p) * wt; a1 += bfhi(p) * wt;
  }
  float dn = dinv[gw], ws = dn * dn;
  uint32_t p = xb[(size_t)gw * 64 + lane];
  a0 += bflo(p) * ws; a1 += bfhi(p) * ws;
  outb[(size_t)gw * 64 + lane] = pack_bf2(a0, a1);
}

__global__ __launch_bounds__(256) void agg_ln_kernel(const uint32_t* __restrict__ hb,
                                                     const float* __restrict__ dinv,
                                                     const int* __restrict__ row_ptr,
                                                     const int2* __restrict__ edges,
                                                     const float* __restrict__ bias,
                                                     const float* __restrict__ gamma,
                                                     const float* __restrict__ beta,
                                                     uint32_t* __restrict__ zb, int N) {
  int gw = (blockIdx.x * 256 + threadIdx.x) >> 6;
  int lane = threadIdx.x & 63;
  if (gw >= N) return;
  int e0 = row_ptr[gw], e1 = row_ptr[gw + 1];
  float a0 = 0.f, a1 = 0.f;
  for (int e = e0; e < e1; ++e) {
    int2 ed = edges[e];
    float wt = __int_as_float(ed.y);
    uint32_t p = hb[(size_t)ed.x * 64 + lane];
    a0 += bflo(p) * wt; a1 += bfhi(p) * wt;
  }
  float dn = dinv[gw], ws = dn * dn;
  uint32_t p = hb[(size_t)gw * 64 + lane];
  a0 += bflo(p) * ws; a1 += bfhi(p) * ws;
  int c = lane * 2;
  a0 += bias[c]; a1 += bias[c + 1];
  float s = a0 + a1, ss = a0 * a0 + a1 * a1;
#pragma unroll
  for (int d = 1; d < 64; d <<= 1) {
    s += __shfl_xor(s, d);
    ss += __shfl_xor(ss, d);
  }
  float mu = s * (1.0f / C_OUT);
  float var = ss * (1.0f / C_OUT) - mu * mu;
  float rs = rsqrtf(var + 1e-5f);
  float o0 = fmaxf((a0 - mu) * rs * gamma[c] + beta[c], 0.0f);
  float o1 = fmaxf((a1 - mu) * rs * gamma[c + 1] + beta[c + 1], 0.0f);
  zb[(size_t)gw * 64 + lane] = pack_bf2(o0, o1);
}

// ---------------- Decode (one wave per pair, f32 z) ----------------

__global__ __launch_bounds__(256) void decode_kernel(const float* __restrict__ z,
                                                     const int* __restrict__ eli,
                                                     const float* __restrict__ cutoff,
                                                     float* __restrict__ out, int EL) {
  int gw = (blockIdx.x * 256 + threadIdx.x) >> 6;
  int lane = threadIdx.x & 63;
  if (gw >= EL) return;
  int a = eli[gw];
  int b = eli[EL + gw];
  const float2* z2 = (const float2*)z;
  float2 va = z2[(size_t)a * 64 + lane];
  float2 vb = z2[(size_t)b * 64 + lane];
  float s = va.x * vb.x + va.y * vb.y;
#pragma unroll
  for (int d = 1; d < 64; d <<= 1) s += __shfl_xor(s, d);
  if (lane == 0) {
    out[gw] = s;
    out[EL + gw] = (s < cutoff[0]) ? 0.0f : 1.0f;
  }
}

// ---------------- Launch ----------------

extern "C" void kernel_launch(void* const* d_in, const int* in_sizes, int n_in,
                              void* d_out, int out_size, void* d_ws, size_t ws_size,
                              hipStream_t stream) {
  const float* x        = (const float*)d_in[0];
  const int*   eidx     = (const int*)d_in[1];
  const int*   eli      = (const int*)d_in[2];
  const float* cutoff   = (const float*)d_in[3];
  const float* W1       = (const float*)d_in[4];
  const float* b1       = (const float*)d_in[5];
  const float* bn_gamma = (const float*)d_in[6];
  const float* bn_beta  = (const float*)d_in[7];
  const float* W2       = (const float*)d_in[8];
  const float* b2       = (const float*)d_in[9];
  const float* ln_gamma = (const float*)d_in[10];
  const float* ln_beta  = (const float*)d_in[11];
  const float* lin_W    = (const float*)d_in[12];
  const float* lin_b    = (const float*)d_in[13];
  float* out = (float*)d_out;

  const int N  = in_sizes[0] / C_IN;   // 100000
  const int E  = in_sizes[1] / 2;      // 800000
  const int EL = in_sizes[2] / 2;      // 200000

  const int* src = eidx;
  const int* dst = eidx + E;

  const int MB = (N + 127) / 128;  // 782 row blocks
  const int R  = 2 * MB;           // BN partial rows

  // workspace layout
  char* p = (char*)d_ws;
  short* regionA = (short*)p;  p += (size_t)N * 256 * 2;  // x_bf+xa_bf, later h1n_bf
  short* regionB = (short*)p;  p += (size_t)N * 256 * 2;  // h1_bf, later z_bf
  short* h2_bf   = (short*)p;  p += (size_t)N * 128 * 2;
  float* zfin    = (float*)p;  p += (size_t)N * 128 * 4;
  float* dinv    = (float*)p;  p += (size_t)N * 4;
  int* counts    = (int*)p;    p += (size_t)N * 4;
  int* row_ptr   = (int*)p;    p += (size_t)(N + 4) * 4;
  int* cursor    = (int*)p;    p += (size_t)N * 4;
  int2* edges    = (int2*)p;   p += (size_t)E * 8;
  float* pS      = (float*)p;  p += (size_t)R * C_HID * 4;
  float* pSS     = (float*)p;  p += (size_t)R * C_HID * 4;
  float* oS      = (float*)p;  p += 32 * C_HID * 4;
  float* oSS     = (float*)p;  p += 32 * C_HID * 4;
  float* bnp     = (float*)p;  p += 2 * C_HID * 4;
  short* w1t     = (short*)p;  p += (size_t)C_HID * C_IN * 2;
  short* w2t     = (short*)p;  p += (size_t)C_OUT * C_HID * 2;
  short* w3t     = (short*)p;  p += (size_t)C_OUT * C_OUT * 2;

  short* x_bf   = regionA;                      // [N][128]
  short* xa_bf  = regionA + (size_t)N * 128;    // [N][128]
  short* h1_bf  = regionB;                      // [N][256]
  short* h1n_bf = regionA;                      // [N][256] (x/xa dead)
  short* z_bf   = regionB;                      // [N][128] (h1 dead)

  hipMemsetAsync(counts, 0, (size_t)N * 4, stream);

  int eb = (E + 255) / 256;
  int nb = (N + 255) / 256;

  hist_kernel<<<eb, 256, 0, stream>>>(dst, counts, E);
  dinv_kernel<<<nb, 256, 0, stream>>>(counts, dinv, cursor, N);
  scan_kernel<<<1, 1024, 0, stream>>>(counts, row_ptr, N);
  place_kernel<<<eb, 256, 0, stream>>>(src, dst, row_ptr, cursor, dinv, edges, E);

  cvt_wT_kernel<<<(C_IN * C_HID + 255) / 256, 256, 0, stream>>>(W1, w1t, C_IN, C_HID);
  cvt_wT_kernel<<<(C_HID * C_OUT + 255) / 256, 256, 0, stream>>>(W2, w2t, C_HID, C_OUT);
  cvt_wT_kernel<<<(C_OUT * C_OUT + 255) / 256, 256, 0, stream>>>(lin_W, w3t, C_OUT, C_OUT);

  int xn4 = N * C_IN / 4;
  cvt_bf16_kernel<<<(xn4 + 255) / 256, 256, 0, stream>>>(x, x_bf, xn4);

  int wb = ((size_t)N * 64 + 255) / 256;  // one wave per node
  agg_x_kernel<<<wb, 256, 0, stream>>>((const uint32_t*)x_bf, dinv, row_ptr, edges,
                                       (uint32_t*)xa_bf, N);

  // GEMM1: h1 = agg(x) @ W1 + b1  [N x 256] bf16 + BN partials
  dim3 g1(C_HID / 128, MB);
  bgemm_big<2><<<g1, 256, 0, stream>>>(xa_bf, w1t, b1, h1_bf, pS, pSS, N, C_HID, C_IN);

  bn_red1_kernel<<<32, 256, 0, stream>>>(pS, pSS, oS, oSS, R);
  bn_red2_kernel<<<1, 256, 0, stream>>>(oS, oSS, bn_gamma, bn_beta, bnp, 32,
                                        1.0f / (float)N);

  int bnb = ((size_t)N * 128 + 255) / 256;
  bn_apply_kernel<<<bnb, 256, 0, stream>>>((const uint32_t*)h1_bf, bnp,
                                           (uint32_t*)h1n_bf, N * 128);

  // GEMM2: h2raw = h1n @ W2  [N x 128] bf16 (bias b2 added in agg_ln)
  dim3 g2(C_OUT / 128, MB);
  bgemm_big<1><<<g2, 256, 0, stream>>>(h1n_bf, w2t, nullptr, h2_bf, nullptr, nullptr,
                                       N, C_OUT, C_HID);

  agg_ln_kernel<<<wb, 256, 0, stream>>>((const uint32_t*)h2_bf, dinv, row_ptr, edges,
                                        b2, ln_gamma, ln_beta, (uint32_t*)z_bf, N);

  // GEMM3: zfin = z @ lin_W + lin_b  [N x 128] f32
  dim3 g3(C_OUT / 128, MB);
  bgemm_big<0><<<g3, 256, 0, stream>>>(z_bf, w3t, lin_b, zfin, nullptr, nullptr,
                                       N, C_OUT, C_OUT);

  int db = ((size_t)EL * 64 + 255) / 256;
  decode_kernel<<<db, 256, 0, stream>>>(zfin, eli, cutoff, out, EL);
}

// Round 5
// 502.126 us; speedup vs baseline: 2.0331x; 1.2381x over previous
//
#include <hip/hip_runtime.h>
#include <stdint.h>

// ---------------------------------------------------------------------------
// Net_60129542953 R5:
//  - Gather kernels restructured for memory-level parallelism:
//    agg_x/agg_ln use 16-lane groups (4 nodes/wave), uint4 row loads,
//    edge-loop unrolled x4 (up to 16 outstanding gathers per wave).
//    decode uses 32-lane groups (2 pairs/wave) with float4 loads.
//  - R4's latency-bound 1-load-in-flight loop was the 94us bottleneck.
// ---------------------------------------------------------------------------

#define C_IN  128
#define C_HID 256
#define C_OUT 128

typedef __attribute__((ext_vector_type(8))) short bf16x8;
typedef __attribute__((ext_vector_type(4))) float f32x4;

__device__ __forceinline__ short f2bf(float f) {
  union { float f; uint32_t u; } v; v.f = f;
  uint32_t r = v.u + 0x7FFFu + ((v.u >> 16) & 1u);  // RNE
  return (short)(r >> 16);
}
__device__ __forceinline__ uint32_t pack_bf2(float a, float b) {
  return (uint32_t)(uint16_t)f2bf(a) | ((uint32_t)(uint16_t)f2bf(b) << 16);
}
__device__ __forceinline__ float bflo(uint32_t p) {
  union { uint32_t u; float f; } v; v.u = p << 16; return v.f;
}
__device__ __forceinline__ float bfhi(uint32_t p) {
  union { uint32_t u; float f; } v; v.u = p & 0xffff0000u; return v.f;
}

__device__ __forceinline__ void acc8(float* a, uint4 p, float w) {
  a[0] += bflo(p.x) * w; a[1] += bfhi(p.x) * w;
  a[2] += bflo(p.y) * w; a[3] += bfhi(p.y) * w;
  a[4] += bflo(p.z) * w; a[5] += bfhi(p.z) * w;
  a[6] += bflo(p.w) * w; a[7] += bfhi(p.w) * w;
}

__device__ __forceinline__ void async_cp16(const void* g, void* l) {
  __builtin_amdgcn_global_load_lds((const __attribute__((address_space(1))) void*)g,
                                   (__attribute__((address_space(3))) void*)l, 16, 0, 0);
}

// ---------------- CSR build ----------------

__global__ __launch_bounds__(256) void hist_kernel(const int* __restrict__ dst,
                                                   int* __restrict__ counts, int E) {
  int e = blockIdx.x * 256 + threadIdx.x;
  if (e < E) atomicAdd(&counts[dst[e]], 1);
}

__global__ __launch_bounds__(256) void dinv_kernel(const int* __restrict__ counts,
                                                   float* __restrict__ dinv,
                                                   int* __restrict__ cursor, int N) {
  int n = blockIdx.x * 256 + threadIdx.x;
  if (n < N) {
    dinv[n] = rsqrtf((float)counts[n] + 1.0f);  // deg = indeg + 1 (self loop)
    cursor[n] = 0;
  }
}

__global__ __launch_bounds__(1024) void scan_kernel(const int* __restrict__ counts,
                                                    int* __restrict__ row_ptr, int n) {
  __shared__ int wsum[16];
  int tid = threadIdx.x;
  int lane = tid & 63, wid = tid >> 6;
  int carry = 0;
  for (int base = 0; base <= n; base += 1024) {
    int idx = base + tid;
    int v = (idx < n) ? counts[idx] : 0;
    int x = v;
#pragma unroll
    for (int d = 1; d < 64; d <<= 1) {
      int y = __shfl_up(x, d, 64);
      if (lane >= d) x += y;
    }
    if (lane == 63) wsum[wid] = x;
    __syncthreads();
    if (tid == 0) {
      int run = carry;
#pragma unroll
      for (int w = 0; w < 16; ++w) { int t = wsum[w]; wsum[w] = run; run += t; }
      carry = run;
    }
    __syncthreads();
    if (idx <= n) row_ptr[idx] = wsum[wid] + x - v;
    __syncthreads();
  }
}

// edges[pos] = {src, dinv[src]*dinv[dst]}
__global__ __launch_bounds__(256) void place_kernel(const int* __restrict__ src,
                                                    const int* __restrict__ dst,
                                                    const int* __restrict__ row_ptr,
                                                    int* __restrict__ cursor,
                                                    const float* __restrict__ dinv,
                                                    int2* __restrict__ edges, int E) {
  int e = blockIdx.x * 256 + threadIdx.x;
  if (e < E) {
    int d = dst[e], s = src[e];
    int pos = row_ptr[d] + atomicAdd(&cursor[d], 1);
    int2 ed; ed.x = s; ed.y = __float_as_int(dinv[s] * dinv[d]);
    edges[pos] = ed;
  }
}

// ---------------- Conversions ----------------

__global__ __launch_bounds__(256) void cvt_bf16_kernel(const float* __restrict__ in,
                                                       short* __restrict__ out, int n4) {
  int i = blockIdx.x * 256 + threadIdx.x;
  if (i >= n4) return;
  float4 v = ((const float4*)in)[i];
  short4 o;
  o.x = f2bf(v.x); o.y = f2bf(v.y); o.z = f2bf(v.z); o.w = f2bf(v.w);
  ((short4*)out)[i] = o;
}

// W[K,N] f32 -> WT[N,K] bf16
__global__ __launch_bounds__(256) void cvt_wT_kernel(const float* __restrict__ W,
                                                     short* __restrict__ WT, int K, int N) {
  int i = blockIdx.x * 256 + threadIdx.x;
  if (i >= K * N) return;
  int k = i / N, n = i - k * N;
  WT[(size_t)n * K + k] = f2bf(W[i]);
}

// ---------------- bf16 MFMA GEMM: C[M,N] = A[M,K] @ BT[N,K]^T (+bias) -------
// 128x128 tile, BK=128 (one LDS drain per chunk), 4 waves 2x2, wave = 64x64.
// XOR-swizzled LDS; LDS-staged coalesced C stores.
// MODE 0: f32 out; 1: bf16 out; 2: bf16 out + non-atomic BN partials.

template <int MODE>
__global__ __launch_bounds__(256, 2) void bgemm_big(const short* __restrict__ A,
                                                    const short* __restrict__ BT,
                                                    const float* __restrict__ bias,
                                                    void* __restrict__ Cout,
                                                    float* __restrict__ pS,
                                                    float* __restrict__ pSS,
                                                    int M, int N, int K) {
  __shared__ short smem[2 * 128 * 128];  // 64 KB
  short* As = smem;
  short* Bs = smem + 128 * 128;
  const int tid = threadIdx.x;
  const int w = tid >> 6, lane = tid & 63;
  const int wM = w >> 1, wN = w & 1;
  const int rowBase = blockIdx.y * 128;
  const int colBase = blockIdx.x * 128;
  const int l15 = lane & 15, q = lane >> 4;

  f32x4 acc[4][4];
#pragma unroll
  for (int i = 0; i < 4; ++i)
#pragma unroll
    for (int j = 0; j < 4; ++j) acc[i][j] = (f32x4){0.f, 0.f, 0.f, 0.f};

  for (int k0 = 0; k0 < K; k0 += 128) {
#pragma unroll
    for (int it = 0; it < 8; ++it) {
      int p = it * 256 + tid;
      int row = p >> 4, kcp = p & 15;
      int kc = kcp ^ (row & 15);
      int gm = rowBase + row; if (gm >= M) gm = M - 1;  // clamp; stores guarded
      async_cp16(A + (size_t)gm * K + k0 + kc * 8, &As[(it * 256 + w * 64) * 8]);
    }
#pragma unroll
    for (int it = 0; it < 8; ++it) {
      int p = it * 256 + tid;
      int row = p >> 4, kcp = p & 15;
      int kc = kcp ^ (row & 15);
      async_cp16(BT + (size_t)(colBase + row) * K + k0 + kc * 8,
                 &Bs[(it * 256 + w * 64) * 8]);
    }
    __syncthreads();  // single drain for the whole 64 KB stage

#pragma unroll
    for (int ks = 0; ks < 4; ++ks) {
      bf16x8 af[4], bfr[4];
#pragma unroll
      for (int tm = 0; tm < 4; ++tm) {
        int row = wM * 64 + tm * 16 + l15;
        int kcp = (ks * 4 + q) ^ l15;
        af[tm] = *(const bf16x8*)&As[(row * 16 + kcp) * 8];
      }
#pragma unroll
      for (int tn = 0; tn < 4; ++tn) {
        int row = wN * 64 + tn * 16 + l15;
        int kcp = (ks * 4 + q) ^ l15;
        bfr[tn] = *(const bf16x8*)&Bs[(row * 16 + kcp) * 8];
      }
#pragma unroll
      for (int tm = 0; tm < 4; ++tm)
#pragma unroll
        for (int tn = 0; tn < 4; ++tn)
          acc[tm][tn] = __builtin_amdgcn_mfma_f32_16x16x32_bf16(af[tm], bfr[tn],
                                                                acc[tm][tn], 0, 0, 0);
    }
    __syncthreads();
  }

  if (MODE == 2) {
#pragma unroll
    for (int tn = 0; tn < 4; ++tn) {
      int col = colBase + wN * 64 + tn * 16 + l15;
      float bv = bias ? bias[col] : 0.0f;
      float s = 0.f, ss = 0.f;
#pragma unroll
      for (int tm = 0; tm < 4; ++tm) {
        int r0 = rowBase + wM * 64 + tm * 16 + q * 4;
#pragma unroll
        for (int r = 0; r < 4; ++r) {
          if (r0 + r < M) { float v = acc[tm][tn][r] + bv; s += v; ss += v * v; }
        }
      }
      s += __shfl_xor(s, 16); s += __shfl_xor(s, 32);
      ss += __shfl_xor(ss, 16); ss += __shfl_xor(ss, 32);
      if (q == 0) {
        int prow = blockIdx.y * 2 + wM;
        pS[(size_t)prow * C_HID + col] = s;
        pSS[(size_t)prow * C_HID + col] = ss;
      }
    }
  }

  if (MODE == 0) {
    float* S = (float*)smem;
#pragma unroll
    for (int tn = 0; tn < 4; ++tn) {
      int col = wN * 64 + tn * 16 + l15;
      float bv = bias ? bias[colBase + col] : 0.0f;
#pragma unroll
      for (int tm = 0; tm < 4; ++tm) {
        int r0 = wM * 64 + tm * 16 + q * 4;
#pragma unroll
        for (int r = 0; r < 4; ++r) S[(r0 + r) * 128 + col] = acc[tm][tn][r] + bv;
      }
    }
    __syncthreads();
    float* Cf = (float*)Cout;
#pragma unroll
    for (int it = 0; it < 16; ++it) {
      int p = it * 256 + tid;
      int row = p >> 5, c = p & 31;
      int gm = rowBase + row;
      if (gm < M)
        *(uint4*)&Cf[(size_t)gm * N + colBase + c * 4] = ((const uint4*)S)[p];
    }
  } else {
    short* S = As;
#pragma unroll
    for (int tn = 0; tn < 4; ++tn) {
      int col = wN * 64 + tn * 16 + l15;
      float bv = bias ? bias[colBase + col] : 0.0f;
#pragma unroll
      for (int tm = 0; tm < 4; ++tm) {
        int r0 = wM * 64 + tm * 16 + q * 4;
#pragma unroll
        for (int r = 0; r < 4; ++r) S[(r0 + r) * 128 + col] = f2bf(acc[tm][tn][r] + bv);
      }
    }
    __syncthreads();
    short* Cb = (short*)Cout;
#pragma unroll
    for (int it = 0; it < 8; ++it) {
      int p = it * 256 + tid;
      int row = p >> 4, c = p & 15;
      int gm = rowBase + row;
      if (gm < M)
        *(uint4*)&Cb[(size_t)gm * N + colBase + c * 8] = ((const uint4*)S)[p];
    }
  }
}

// ---------------- BN stats tree reduce ----------------

__global__ __launch_bounds__(256) void bn_red1_kernel(const float* __restrict__ pS,
                                                      const float* __restrict__ pSS,
                                                      float* __restrict__ oS,
                                                      float* __restrict__ oSS, int R) {
  int c = threadIdx.x;
  int per = (R + gridDim.x - 1) / gridDim.x;
  int r0 = blockIdx.x * per, r1 = min(R, r0 + per);
  float s = 0.f, ss = 0.f;
  for (int r = r0; r < r1; ++r) {
    s += pS[(size_t)r * C_HID + c];
    ss += pSS[(size_t)r * C_HID + c];
  }
  oS[(size_t)blockIdx.x * C_HID + c] = s;
  oSS[(size_t)blockIdx.x * C_HID + c] = ss;
}

__global__ __launch_bounds__(256) void bn_red2_kernel(const float* __restrict__ oS,
                                                      const float* __restrict__ oSS,
                                                      const float* __restrict__ gamma,
                                                      const float* __restrict__ beta,
                                                      float* __restrict__ bnp,
                                                      int G, float invN) {
  int c = threadIdx.x;
  float s = 0.f, ss = 0.f;
  for (int g = 0; g < G; ++g) {
    s += oS[(size_t)g * C_HID + c];
    ss += oSS[(size_t)g * C_HID + c];
  }
  float mu = s * invN;
  float var = ss * invN - mu * mu;
  float sc = gamma[c] * rsqrtf(var + 1e-5f);
  bnp[c] = sc;
  bnp[C_HID + c] = beta[c] - mu * sc;
}

// ---------------- BatchNorm apply (bf16 -> bf16 relu'd) ----------------

__global__ __launch_bounds__(256) void bn_apply_kernel(const uint32_t* __restrict__ hb,
                                                       const float* __restrict__ bnp,
                                                       uint32_t* __restrict__ ob,
                                                       int total) {
  int i = blockIdx.x * 256 + threadIdx.x;
  if (i >= total) return;
  int c = (i & 127) * 2;
  float sc0 = bnp[c], sc1 = bnp[c + 1];
  float sh0 = bnp[C_HID + c], sh1 = bnp[C_HID + c + 1];
  uint32_t p = hb[i];
  float o0 = fmaxf(bflo(p) * sc0 + sh0, 0.0f);
  float o1 = fmaxf(bfhi(p) * sc1 + sh1, 0.0f);
  ob[i] = pack_bf2(o0, o1);
}

// ---------------- Aggregations: 16-lane group per node, unroll x4 ----------
// Row = 128 bf16 = 16 uint4; lane sl owns channels sl*8..sl*8+7.

__global__ __launch_bounds__(256) void agg_x_kernel(const uint4* __restrict__ xb4,
                                                    const float* __restrict__ dinv,
                                                    const int* __restrict__ row_ptr,
                                                    const int2* __restrict__ edges,
                                                    uint4* __restrict__ out4, int N) {
  int g = (blockIdx.x * 256 + threadIdx.x) >> 4;
  int sl = threadIdx.x & 15;
  if (g >= N) return;
  int e0 = row_ptr[g], e1 = row_ptr[g + 1];
  float a[8] = {0.f, 0.f, 0.f, 0.f, 0.f, 0.f, 0.f, 0.f};
  int e = e0;
  for (; e + 4 <= e1; e += 4) {
    int2 ed0 = edges[e], ed1 = edges[e + 1], ed2 = edges[e + 2], ed3 = edges[e + 3];
    uint4 p0 = xb4[(size_t)ed0.x * 16 + sl];
    uint4 p1 = xb4[(size_t)ed1.x * 16 + sl];
    uint4 p2 = xb4[(size_t)ed2.x * 16 + sl];
    uint4 p3 = xb4[(size_t)ed3.x * 16 + sl];
    acc8(a, p0, __int_as_float(ed0.y));
    acc8(a, p1, __int_as_float(ed1.y));
    acc8(a, p2, __int_as_float(ed2.y));
    acc8(a, p3, __int_as_float(ed3.y));
  }
  for (; e < e1; ++e) {
    int2 ed = edges[e];
    uint4 p = xb4[(size_t)ed.x * 16 + sl];
    acc8(a, p, __int_as_float(ed.y));
  }
  float dn = dinv[g];
  uint4 ps = xb4[(size_t)g * 16 + sl];
  acc8(a, ps, dn * dn);
  uint4 o;
  o.x = pack_bf2(a[0], a[1]); o.y = pack_bf2(a[2], a[3]);
  o.z = pack_bf2(a[4], a[5]); o.w = pack_bf2(a[6], a[7]);
  out4[(size_t)g * 16 + sl] = o;
}

__global__ __launch_bounds__(256) void agg_ln_kernel(const uint4* __restrict__ hb4,
                                                     const float* __restrict__ dinv,
                                                     const int* __restrict__ row_ptr,
                                                     const int2* __restrict__ edges,
                                                     const float* __restrict__ bias,
                                                     const float* __restrict__ gamma,
                                                     const float* __restrict__ beta,
                                                     uint4* __restrict__ zb4, int N) {
  int g = (blockIdx.x * 256 + threadIdx.x) >> 4;
  int sl = threadIdx.x & 15;
  if (g >= N) return;
  int e0 = row_ptr[g], e1 = row_ptr[g + 1];
  float a[8] = {0.f, 0.f, 0.f, 0.f, 0.f, 0.f, 0.f, 0.f};
  int e = e0;
  for (; e + 4 <= e1; e += 4) {
    int2 ed0 = edges[e], ed1 = edges[e + 1], ed2 = edges[e + 2], ed3 = edges[e + 3];
    uint4 p0 = hb4[(size_t)ed0.x * 16 + sl];
    uint4 p1 = hb4[(size_t)ed1.x * 16 + sl];
    uint4 p2 = hb4[(size_t)ed2.x * 16 + sl];
    uint4 p3 = hb4[(size_t)ed3.x * 16 + sl];
    acc8(a, p0, __int_as_float(ed0.y));
    acc8(a, p1, __int_as_float(ed1.y));
    acc8(a, p2, __int_as_float(ed2.y));
    acc8(a, p3, __int_as_float(ed3.y));
  }
  for (; e < e1; ++e) {
    int2 ed = edges[e];
    uint4 p = hb4[(size_t)ed.x * 16 + sl];
    acc8(a, p, __int_as_float(ed.y));
  }
  float dn = dinv[g];
  uint4 ps = hb4[(size_t)g * 16 + sl];
  acc8(a, ps, dn * dn);

  int c = sl * 8;
  float4 bv0 = *(const float4*)&bias[c];
  float4 bv1 = *(const float4*)&bias[c + 4];
  a[0] += bv0.x; a[1] += bv0.y; a[2] += bv0.z; a[3] += bv0.w;
  a[4] += bv1.x; a[5] += bv1.y; a[6] += bv1.z; a[7] += bv1.w;

  float s = 0.f, ss = 0.f;
#pragma unroll
  for (int j = 0; j < 8; ++j) { s += a[j]; ss += a[j] * a[j]; }
#pragma unroll
  for (int d = 1; d < 16; d <<= 1) {  // reduce within the 16-lane group
    s += __shfl_xor(s, d);
    ss += __shfl_xor(ss, d);
  }
  float mu = s * (1.0f / C_OUT);
  float var = ss * (1.0f / C_OUT) - mu * mu;
  float rs = rsqrtf(var + 1e-5f);
  float4 g0 = *(const float4*)&gamma[c];
  float4 g1 = *(const float4*)&gamma[c + 4];
  float4 t0 = *(const float4*)&beta[c];
  float4 t1 = *(const float4*)&beta[c + 4];
  float o[8];
  o[0] = fmaxf((a[0] - mu) * rs * g0.x + t0.x, 0.0f);
  o[1] = fmaxf((a[1] - mu) * rs * g0.y + t0.y, 0.0f);
  o[2] = fmaxf((a[2] - mu) * rs * g0.z + t0.z, 0.0f);
  o[3] = fmaxf((a[3] - mu) * rs * g0.w + t0.w, 0.0f);
  o[4] = fmaxf((a[4] - mu) * rs * g1.x + t1.x, 0.0f);
  o[5] = fmaxf((a[5] - mu) * rs * g1.y + t1.y, 0.0f);
  o[6] = fmaxf((a[6] - mu) * rs * g1.z + t1.z, 0.0f);
  o[7] = fmaxf((a[7] - mu) * rs * g1.w + t1.w, 0.0f);
  uint4 ov;
  ov.x = pack_bf2(o[0], o[1]); ov.y = pack_bf2(o[2], o[3]);
  ov.z = pack_bf2(o[4], o[5]); ov.w = pack_bf2(o[6], o[7]);
  zb4[(size_t)g * 16 + sl] = ov;
}

// ---------------- Decode: 32-lane group per pair, float4 loads --------------

__global__ __launch_bounds__(256) void decode_kernel(const float4* __restrict__ z4,
                                                     const int* __restrict__ eli,
                                                     const float* __restrict__ cutoff,
                                                     float* __restrict__ out, int EL) {
  int g = (blockIdx.x * 256 + threadIdx.x) >> 5;
  int sl = threadIdx.x & 31;
  if (g >= EL) return;
  int a = eli[g];
  int b = eli[EL + g];
  float4 va = z4[(size_t)a * 32 + sl];
  float4 vb = z4[(size_t)b * 32 + sl];
  float s = va.x * vb.x + va.y * vb.y + va.z * vb.z + va.w * vb.w;
#pragma unroll
  for (int d = 1; d < 32; d <<= 1) s += __shfl_xor(s, d);
  if (sl == 0) {
    out[g] = s;
    out[EL + g] = (s < cutoff[0]) ? 0.0f : 1.0f;
  }
}

// ---------------- Launch ----------------

extern "C" void kernel_launch(void* const* d_in, const int* in_sizes, int n_in,
                              void* d_out, int out_size, void* d_ws, size_t ws_size,
                              hipStream_t stream) {
  const float* x        = (const float*)d_in[0];
  const int*   eidx     = (const int*)d_in[1];
  const int*   eli      = (const int*)d_in[2];
  const float* cutoff   = (const float*)d_in[3];
  const float* W1       = (const float*)d_in[4];
  const float* b1       = (const float*)d_in[5];
  const float* bn_gamma = (const float*)d_in[6];
  const float* bn_beta  = (const float*)d_in[7];
  const float* W2       = (const float*)d_in[8];
  const float* b2       = (const float*)d_in[9];
  const float* ln_gamma = (const float*)d_in[10];
  const float* ln_beta  = (const float*)d_in[11];
  const float* lin_W    = (const float*)d_in[12];
  const float* lin_b    = (const float*)d_in[13];
  float* out = (float*)d_out;

  const int N  = in_sizes[0] / C_IN;   // 100000
  const int E  = in_sizes[1] / 2;      // 800000
  const int EL = in_sizes[2] / 2;      // 200000

  const int* src = eidx;
  const int* dst = eidx + E;

  const int MB = (N + 127) / 128;
  const int R  = 2 * MB;

  // workspace layout
  char* p = (char*)d_ws;
  short* regionA = (short*)p;  p += (size_t)N * 256 * 2;  // x_bf+xa_bf, later h1n_bf
  short* regionB = (short*)p;  p += (size_t)N * 256 * 2;  // h1_bf, later z_bf
  short* h2_bf   = (short*)p;  p += (size_t)N * 128 * 2;
  float* zfin    = (float*)p;  p += (size_t)N * 128 * 4;
  float* dinv    = (float*)p;  p += (size_t)N * 4;
  int* counts    = (int*)p;    p += (size_t)N * 4;
  int* row_ptr   = (int*)p;    p += (size_t)(N + 4) * 4;
  int* cursor    = (int*)p;    p += (size_t)N * 4;
  int2* edges    = (int2*)p;   p += (size_t)E * 8;
  float* pS      = (float*)p;  p += (size_t)R * C_HID * 4;
  float* pSS     = (float*)p;  p += (size_t)R * C_HID * 4;
  float* oS      = (float*)p;  p += 32 * C_HID * 4;
  float* oSS     = (float*)p;  p += 32 * C_HID * 4;
  float* bnp     = (float*)p;  p += 2 * C_HID * 4;
  short* w1t     = (short*)p;  p += (size_t)C_HID * C_IN * 2;
  short* w2t     = (short*)p;  p += (size_t)C_OUT * C_HID * 2;
  short* w3t     = (short*)p;  p += (size_t)C_OUT * C_OUT * 2;

  short* x_bf   = regionA;
  short* xa_bf  = regionA + (size_t)N * 128;
  short* h1_bf  = regionB;
  short* h1n_bf = regionA;
  short* z_bf   = regionB;

  hipMemsetAsync(counts, 0, (size_t)N * 4, stream);

  int eb = (E + 255) / 256;
  int nb = (N + 255) / 256;

  hist_kernel<<<eb, 256, 0, stream>>>(dst, counts, E);
  dinv_kernel<<<nb, 256, 0, stream>>>(counts, dinv, cursor, N);
  scan_kernel<<<1, 1024, 0, stream>>>(counts, row_ptr, N);
  place_kernel<<<eb, 256, 0, stream>>>(src, dst, row_ptr, cursor, dinv, edges, E);

  cvt_wT_kernel<<<(C_IN * C_HID + 255) / 256, 256, 0, stream>>>(W1, w1t, C_IN, C_HID);
  cvt_wT_kernel<<<(C_HID * C_OUT + 255) / 256, 256, 0, stream>>>(W2, w2t, C_HID, C_OUT);
  cvt_wT_kernel<<<(C_OUT * C_OUT + 255) / 256, 256, 0, stream>>>(lin_W, w3t, C_OUT, C_OUT);

  int xn4 = N * C_IN / 4;
  cvt_bf16_kernel<<<(xn4 + 255) / 256, 256, 0, stream>>>(x, x_bf, xn4);

  int gb = ((size_t)N * 16 + 255) / 256;  // 16-lane group per node
  agg_x_kernel<<<gb, 256, 0, stream>>>((const uint4*)x_bf, dinv, row_ptr, edges,
                                       (uint4*)xa_bf, N);

  // GEMM1: h1 = agg(x) @ W1 + b1  [N x 256] bf16 + BN partials
  dim3 g1(C_HID / 128, MB);
  bgemm_big<2><<<g1, 256, 0, stream>>>(xa_bf, w1t, b1, h1_bf, pS, pSS, N, C_HID, C_IN);

  bn_red1_kernel<<<32, 256, 0, stream>>>(pS, pSS, oS, oSS, R);
  bn_red2_kernel<<<1, 256, 0, stream>>>(oS, oSS, bn_gamma, bn_beta, bnp, 32,
                                        1.0f / (float)N);

  int bnb = ((size_t)N * 128 + 255) / 256;
  bn_apply_kernel<<<bnb, 256, 0, stream>>>((const uint32_t*)h1_bf, bnp,
                                           (uint32_t*)h1n_bf, N * 128);

  // GEMM2: h2raw = h1n @ W2  [N x 128] bf16 (bias b2 added in agg_ln)
  dim3 g2(C_OUT / 128, MB);
  bgemm_big<1><<<g2, 256, 0, stream>>>(h1n_bf, w2t, nullptr, h2_bf, nullptr, nullptr,
                                       N, C_OUT, C_HID);

  agg_ln_kernel<<<gb, 256, 0, stream>>>((const uint4*)h2_bf, dinv, row_ptr, edges,
                                        b2, ln_gamma, ln_beta, (uint4*)z_bf, N);

  // GEMM3: zfin = z @ lin_W + lin_b  [N x 128] f32
  dim3 g3(C_OUT / 128, MB);
  bgemm_big<0><<<g3, 256, 0, stream>>>(z_bf, w3t, lin_b, zfin, nullptr, nullptr,
                                       N, C_OUT, C_OUT);

  int db = ((size_t)EL * 32 + 255) / 256;  // 32-lane group per pair
  decode_kernel<<<db, 256, 0, stream>>>((const float4*)zfin, eli, cutoff, out, EL);
}

// Round 6
// 431.645 us; speedup vs baseline: 2.3651x; 1.1633x over previous
//
#include <hip/hip_runtime.h>
#include <stdint.h>

// ---------------------------------------------------------------------------
// Net_60129542953 R6:
//  - Single-block scan (81us, fully serialized on 1 CU) replaced with a
//    3-phase device-wide scan (256 blocks): part-sums -> scan sums -> final.
//  - Everything else unchanged from R5.
// ---------------------------------------------------------------------------

#define C_IN  128
#define C_HID 256
#define C_OUT 128
#define SCAN_B 256

typedef __attribute__((ext_vector_type(8))) short bf16x8;
typedef __attribute__((ext_vector_type(4))) float f32x4;

__device__ __forceinline__ short f2bf(float f) {
  union { float f; uint32_t u; } v; v.f = f;
  uint32_t r = v.u + 0x7FFFu + ((v.u >> 16) & 1u);  // RNE
  return (short)(r >> 16);
}
__device__ __forceinline__ uint32_t pack_bf2(float a, float b) {
  return (uint32_t)(uint16_t)f2bf(a) | ((uint32_t)(uint16_t)f2bf(b) << 16);
}
__device__ __forceinline__ float bflo(uint32_t p) {
  union { uint32_t u; float f; } v; v.u = p << 16; return v.f;
}
__device__ __forceinline__ float bfhi(uint32_t p) {
  union { uint32_t u; float f; } v; v.u = p & 0xffff0000u; return v.f;
}

__device__ __forceinline__ void acc8(float* a, uint4 p, float w) {
  a[0] += bflo(p.x) * w; a[1] += bfhi(p.x) * w;
  a[2] += bflo(p.y) * w; a[3] += bfhi(p.y) * w;
  a[4] += bflo(p.z) * w; a[5] += bfhi(p.z) * w;
  a[6] += bflo(p.w) * w; a[7] += bfhi(p.w) * w;
}

__device__ __forceinline__ void async_cp16(const void* g, void* l) {
  __builtin_amdgcn_global_load_lds((const __attribute__((address_space(1))) void*)g,
                                   (__attribute__((address_space(3))) void*)l, 16, 0, 0);
}

// ---------------- CSR build ----------------

__global__ __launch_bounds__(256) void hist_kernel(const int* __restrict__ dst,
                                                   int* __restrict__ counts, int E) {
  int e = blockIdx.x * 256 + threadIdx.x;
  if (e < E) atomicAdd(&counts[dst[e]], 1);
}

__global__ __launch_bounds__(256) void dinv_kernel(const int* __restrict__ counts,
                                                   float* __restrict__ dinv,
                                                   int* __restrict__ cursor, int N) {
  int n = blockIdx.x * 256 + threadIdx.x;
  if (n < N) {
    dinv[n] = rsqrtf((float)counts[n] + 1.0f);  // deg = indeg + 1 (self loop)
    cursor[n] = 0;
  }
}

// ---- 3-phase device-wide exclusive scan of counts[0..n) into row_ptr[0..n] --

// phase A: block b sums its chunk of counts
__global__ __launch_bounds__(256) void scan_part(const int* __restrict__ counts,
                                                 int* __restrict__ blockSums,
                                                 int n, int per) {
  __shared__ int ws[4];
  int b = blockIdx.x;
  int start = b * per, end = min(n, start + per);
  int s = 0;
  for (int i = start + threadIdx.x; i < end; i += 256) s += counts[i];
#pragma unroll
  for (int d = 1; d < 64; d <<= 1) s += __shfl_xor(s, d);
  if ((threadIdx.x & 63) == 0) ws[threadIdx.x >> 6] = s;
  __syncthreads();
  if (threadIdx.x == 0) blockSums[b] = ws[0] + ws[1] + ws[2] + ws[3];
}

// phase B: one block exclusive-scans blockSums[0..B)
__global__ __launch_bounds__(256) void scan_bsums(const int* __restrict__ blockSums,
                                                  int* __restrict__ blockOffs, int B) {
  __shared__ int wsum[4];
  int tid = threadIdx.x, lane = tid & 63, wid = tid >> 6;
  int v = (tid < B) ? blockSums[tid] : 0;
  int x = v;
#pragma unroll
  for (int d = 1; d < 64; d <<= 1) {
    int y = __shfl_up(x, d, 64);
    if (lane >= d) x += y;
  }
  if (lane == 63) wsum[wid] = x;
  __syncthreads();
  if (tid == 0) {
    int run = 0;
#pragma unroll
    for (int w = 0; w < 4; ++w) { int t = wsum[w]; wsum[w] = run; run += t; }
  }
  __syncthreads();
  if (tid < B) blockOffs[tid] = wsum[wid] + x - v;
}

// phase C: block b scans its chunk with base offset, writes row_ptr[0..n]
__global__ __launch_bounds__(256) void scan_final(const int* __restrict__ counts,
                                                  const int* __restrict__ blockOffs,
                                                  int* __restrict__ row_ptr,
                                                  int n, int per) {
  __shared__ int wsum[4];
  __shared__ int sbase;
  int tid = threadIdx.x, lane = tid & 63, wid = tid >> 6;
  int b = blockIdx.x;
  int start = b * per, end = min(n + 1, start + per);
  if (tid == 0) sbase = blockOffs[b];
  __syncthreads();
  for (int chunk = start; chunk < end; chunk += 256) {
    int idx = chunk + tid;
    int v = (idx < n) ? counts[idx] : 0;
    int x = v;
#pragma unroll
    for (int d = 1; d < 64; d <<= 1) {
      int y = __shfl_up(x, d, 64);
      if (lane >= d) x += y;
    }
    if (lane == 63) wsum[wid] = x;
    __syncthreads();
    if (tid == 0) {
      int run = sbase;
#pragma unroll
      for (int w = 0; w < 4; ++w) { int t = wsum[w]; wsum[w] = run; run += t; }
      sbase = run;
    }
    __syncthreads();
    if (idx < end) row_ptr[idx] = wsum[wid] + x - v;
    __syncthreads();
  }
}

// edges[pos] = {src, dinv[src]*dinv[dst]}
__global__ __launch_bounds__(256) void place_kernel(const int* __restrict__ src,
                                                    const int* __restrict__ dst,
                                                    const int* __restrict__ row_ptr,
                                                    int* __restrict__ cursor,
                                                    const float* __restrict__ dinv,
                                                    int2* __restrict__ edges, int E) {
  int e = blockIdx.x * 256 + threadIdx.x;
  if (e < E) {
    int d = dst[e], s = src[e];
    int pos = row_ptr[d] + atomicAdd(&cursor[d], 1);
    int2 ed; ed.x = s; ed.y = __float_as_int(dinv[s] * dinv[d]);
    edges[pos] = ed;
  }
}

// ---------------- Conversions ----------------

__global__ __launch_bounds__(256) void cvt_bf16_kernel(const float* __restrict__ in,
                                                       short* __restrict__ out, int n4) {
  int i = blockIdx.x * 256 + threadIdx.x;
  if (i >= n4) return;
  float4 v = ((const float4*)in)[i];
  short4 o;
  o.x = f2bf(v.x); o.y = f2bf(v.y); o.z = f2bf(v.z); o.w = f2bf(v.w);
  ((short4*)out)[i] = o;
}

// W[K,N] f32 -> WT[N,K] bf16
__global__ __launch_bounds__(256) void cvt_wT_kernel(const float* __restrict__ W,
                                                     short* __restrict__ WT, int K, int N) {
  int i = blockIdx.x * 256 + threadIdx.x;
  if (i >= K * N) return;
  int k = i / N, n = i - k * N;
  WT[(size_t)n * K + k] = f2bf(W[i]);
}

// ---------------- bf16 MFMA GEMM: C[M,N] = A[M,K] @ BT[N,K]^T (+bias) -------
// 128x128 tile, BK=128, XOR-swizzled LDS, LDS-staged coalesced C stores.
// MODE 0: f32 out; 1: bf16 out; 2: bf16 out + non-atomic BN partials.

template <int MODE>
__global__ __launch_bounds__(256, 2) void bgemm_big(const short* __restrict__ A,
                                                    const short* __restrict__ BT,
                                                    const float* __restrict__ bias,
                                                    void* __restrict__ Cout,
                                                    float* __restrict__ pS,
                                                    float* __restrict__ pSS,
                                                    int M, int N, int K) {
  __shared__ short smem[2 * 128 * 128];  // 64 KB
  short* As = smem;
  short* Bs = smem + 128 * 128;
  const int tid = threadIdx.x;
  const int w = tid >> 6, lane = tid & 63;
  const int wM = w >> 1, wN = w & 1;
  const int rowBase = blockIdx.y * 128;
  const int colBase = blockIdx.x * 128;
  const int l15 = lane & 15, q = lane >> 4;

  f32x4 acc[4][4];
#pragma unroll
  for (int i = 0; i < 4; ++i)
#pragma unroll
    for (int j = 0; j < 4; ++j) acc[i][j] = (f32x4){0.f, 0.f, 0.f, 0.f};

  for (int k0 = 0; k0 < K; k0 += 128) {
#pragma unroll
    for (int it = 0; it < 8; ++it) {
      int p = it * 256 + tid;
      int row = p >> 4, kcp = p & 15;
      int kc = kcp ^ (row & 15);
      int gm = rowBase + row; if (gm >= M) gm = M - 1;  // clamp; stores guarded
      async_cp16(A + (size_t)gm * K + k0 + kc * 8, &As[(it * 256 + w * 64) * 8]);
    }
#pragma unroll
    for (int it = 0; it < 8; ++it) {
      int p = it * 256 + tid;
      int row = p >> 4, kcp = p & 15;
      int kc = kcp ^ (row & 15);
      async_cp16(BT + (size_t)(colBase + row) * K + k0 + kc * 8,
                 &Bs[(it * 256 + w * 64) * 8]);
    }
    __syncthreads();  // single drain for the whole 64 KB stage

#pragma unroll
    for (int ks = 0; ks < 4; ++ks) {
      bf16x8 af[4], bfr[4];
#pragma unroll
      for (int tm = 0; tm < 4; ++tm) {
        int row = wM * 64 + tm * 16 + l15;
        int kcp = (ks * 4 + q) ^ l15;
        af[tm] = *(const bf16x8*)&As[(row * 16 + kcp) * 8];
      }
#pragma unroll
      for (int tn = 0; tn < 4; ++tn) {
        int row = wN * 64 + tn * 16 + l15;
        int kcp = (ks * 4 + q) ^ l15;
        bfr[tn] = *(const bf16x8*)&Bs[(row * 16 + kcp) * 8];
      }
#pragma unroll
      for (int tm = 0; tm < 4; ++tm)
#pragma unroll
        for (int tn = 0; tn < 4; ++tn)
          acc[tm][tn] = __builtin_amdgcn_mfma_f32_16x16x32_bf16(af[tm], bfr[tn],
                                                                acc[tm][tn], 0, 0, 0);
    }
    __syncthreads();
  }

  if (MODE == 2) {
#pragma unroll
    for (int tn = 0; tn < 4; ++tn) {
      int col = colBase + wN * 64 + tn * 16 + l15;
      float bv = bias ? bias[col] : 0.0f;
      float s = 0.f, ss = 0.f;
#pragma unroll
      for (int tm = 0; tm < 4; ++tm) {
        int r0 = rowBase + wM * 64 + tm * 16 + q * 4;
#pragma unroll
        for (int r = 0; r < 4; ++r) {
          if (r0 + r < M) { float v = acc[tm][tn][r] + bv; s += v; ss += v * v; }
        }
      }
      s += __shfl_xor(s, 16); s += __shfl_xor(s, 32);
      ss += __shfl_xor(ss, 16); ss += __shfl_xor(ss, 32);
      if (q == 0) {
        int prow = blockIdx.y * 2 + wM;
        pS[(size_t)prow * C_HID + col] = s;
        pSS[(size_t)prow * C_HID + col] = ss;
      }
    }
  }

  if (MODE == 0) {
    float* S = (float*)smem;
#pragma unroll
    for (int tn = 0; tn < 4; ++tn) {
      int col = wN * 64 + tn * 16 + l15;
      float bv = bias ? bias[colBase + col] : 0.0f;
#pragma unroll
      for (int tm = 0; tm < 4; ++tm) {
        int r0 = wM * 64 + tm * 16 + q * 4;
#pragma unroll
        for (int r = 0; r < 4; ++r) S[(r0 + r) * 128 + col] = acc[tm][tn][r] + bv;
      }
    }
    __syncthreads();
    float* Cf = (float*)Cout;
#pragma unroll
    for (int it = 0; it < 16; ++it) {
      int p = it * 256 + tid;
      int row = p >> 5, c = p & 31;
      int gm = rowBase + row;
      if (gm < M)
        *(uint4*)&Cf[(size_t)gm * N + colBase + c * 4] = ((const uint4*)S)[p];
    }
  } else {
    short* S = As;
#pragma unroll
    for (int tn = 0; tn < 4; ++tn) {
      int col = wN * 64 + tn * 16 + l15;
      float bv = bias ? bias[colBase + col] : 0.0f;
#pragma unroll
      for (int tm = 0; tm < 4; ++tm) {
        int r0 = wM * 64 + tm * 16 + q * 4;
#pragma unroll
        for (int r = 0; r < 4; ++r) S[(r0 + r) * 128 + col] = f2bf(acc[tm][tn][r] + bv);
      }
    }
    __syncthreads();
    short* Cb = (short*)Cout;
#pragma unroll
    for (int it = 0; it < 8; ++it) {
      int p = it * 256 + tid;
      int row = p >> 4, c = p & 15;
      int gm = rowBase + row;
      if (gm < M)
        *(uint4*)&Cb[(size_t)gm * N + colBase + c * 8] = ((const uint4*)S)[p];
    }
  }
}

// ---------------- BN stats tree reduce ----------------

__global__ __launch_bounds__(256) void bn_red1_kernel(const float* __restrict__ pS,
                                                      const float* __restrict__ pSS,
                                                      float* __restrict__ oS,
                                                      float* __restrict__ oSS, int R) {
  int c = threadIdx.x;
  int per = (R + gridDim.x - 1) / gridDim.x;
  int r0 = blockIdx.x * per, r1 = min(R, r0 + per);
  float s = 0.f, ss = 0.f;
  for (int r = r0; r < r1; ++r) {
    s += pS[(size_t)r * C_HID + c];
    ss += pSS[(size_t)r * C_HID + c];
  }
  oS[(size_t)blockIdx.x * C_HID + c] = s;
  oSS[(size_t)blockIdx.x * C_HID + c] = ss;
}

__global__ __launch_bounds__(256) void bn_red2_kernel(const float* __restrict__ oS,
                                                      const float* __restrict__ oSS,
                                                      const float* __restrict__ gamma,
                                                      const float* __restrict__ beta,
                                                      float* __restrict__ bnp,
                                                      int G, float invN) {
  int c = threadIdx.x;
  float s = 0.f, ss = 0.f;
  for (int g = 0; g < G; ++g) {
    s += oS[(size_t)g * C_HID + c];
    ss += oSS[(size_t)g * C_HID + c];
  }
  float mu = s * invN;
  float var = ss * invN - mu * mu;
  float sc = gamma[c] * rsqrtf(var + 1e-5f);
  bnp[c] = sc;
  bnp[C_HID + c] = beta[c] - mu * sc;
}

// ---------------- BatchNorm apply (bf16 -> bf16 relu'd) ----------------

__global__ __launch_bounds__(256) void bn_apply_kernel(const uint32_t* __restrict__ hb,
                                                       const float* __restrict__ bnp,
                                                       uint32_t* __restrict__ ob,
                                                       int total) {
  int i = blockIdx.x * 256 + threadIdx.x;
  if (i >= total) return;
  int c = (i & 127) * 2;
  float sc0 = bnp[c], sc1 = bnp[c + 1];
  float sh0 = bnp[C_HID + c], sh1 = bnp[C_HID + c + 1];
  uint32_t p = hb[i];
  float o0 = fmaxf(bflo(p) * sc0 + sh0, 0.0f);
  float o1 = fmaxf(bfhi(p) * sc1 + sh1, 0.0f);
  ob[i] = pack_bf2(o0, o1);
}

// ---------------- Aggregations: 16-lane group per node, unroll x4 ----------

__global__ __launch_bounds__(256) void agg_x_kernel(const uint4* __restrict__ xb4,
                                                    const float* __restrict__ dinv,
                                                    const int* __restrict__ row_ptr,
                                                    const int2* __restrict__ edges,
                                                    uint4* __restrict__ out4, int N) {
  int g = (blockIdx.x * 256 + threadIdx.x) >> 4;
  int sl = threadIdx.x & 15;
  if (g >= N) return;
  int e0 = row_ptr[g], e1 = row_ptr[g + 1];
  float a[8] = {0.f, 0.f, 0.f, 0.f, 0.f, 0.f, 0.f, 0.f};
  int e = e0;
  for (; e + 4 <= e1; e += 4) {
    int2 ed0 = edges[e], ed1 = edges[e + 1], ed2 = edges[e + 2], ed3 = edges[e + 3];
    uint4 p0 = xb4[(size_t)ed0.x * 16 + sl];
    uint4 p1 = xb4[(size_t)ed1.x * 16 + sl];
    uint4 p2 = xb4[(size_t)ed2.x * 16 + sl];
    uint4 p3 = xb4[(size_t)ed3.x * 16 + sl];
    acc8(a, p0, __int_as_float(ed0.y));
    acc8(a, p1, __int_as_float(ed1.y));
    acc8(a, p2, __int_as_float(ed2.y));
    acc8(a, p3, __int_as_float(ed3.y));
  }
  for (; e < e1; ++e) {
    int2 ed = edges[e];
    uint4 p = xb4[(size_t)ed.x * 16 + sl];
    acc8(a, p, __int_as_float(ed.y));
  }
  float dn = dinv[g];
  uint4 ps = xb4[(size_t)g * 16 + sl];
  acc8(a, ps, dn * dn);
  uint4 o;
  o.x = pack_bf2(a[0], a[1]); o.y = pack_bf2(a[2], a[3]);
  o.z = pack_bf2(a[4], a[5]); o.w = pack_bf2(a[6], a[7]);
  out4[(size_t)g * 16 + sl] = o;
}

__global__ __launch_bounds__(256) void agg_ln_kernel(const uint4* __restrict__ hb4,
                                                     const float* __restrict__ dinv,
                                                     const int* __restrict__ row_ptr,
                                                     const int2* __restrict__ edges,
                                                     const float* __restrict__ bias,
                                                     const float* __restrict__ gamma,
                                                     const float* __restrict__ beta,
                                                     uint4* __restrict__ zb4, int N) {
  int g = (blockIdx.x * 256 + threadIdx.x) >> 4;
  int sl = threadIdx.x & 15;
  if (g >= N) return;
  int e0 = row_ptr[g], e1 = row_ptr[g + 1];
  float a[8] = {0.f, 0.f, 0.f, 0.f, 0.f, 0.f, 0.f, 0.f};
  int e = e0;
  for (; e + 4 <= e1; e += 4) {
    int2 ed0 = edges[e], ed1 = edges[e + 1], ed2 = edges[e + 2], ed3 = edges[e + 3];
    uint4 p0 = hb4[(size_t)ed0.x * 16 + sl];
    uint4 p1 = hb4[(size_t)ed1.x * 16 + sl];
    uint4 p2 = hb4[(size_t)ed2.x * 16 + sl];
    uint4 p3 = hb4[(size_t)ed3.x * 16 + sl];
    acc8(a, p0, __int_as_float(ed0.y));
    acc8(a, p1, __int_as_float(ed1.y));
    acc8(a, p2, __int_as_float(ed2.y));
    acc8(a, p3, __int_as_float(ed3.y));
  }
  for (; e < e1; ++e) {
    int2 ed = edges[e];
    uint4 p = hb4[(size_t)ed.x * 16 + sl];
    acc8(a, p, __int_as_float(ed.y));
  }
  float dn = dinv[g];
  uint4 ps = hb4[(size_t)g * 16 + sl];
  acc8(a, ps, dn * dn);

  int c = sl * 8;
  float4 bv0 = *(const float4*)&bias[c];
  float4 bv1 = *(const float4*)&bias[c + 4];
  a[0] += bv0.x; a[1] += bv0.y; a[2] += bv0.z; a[3] += bv0.w;
  a[4] += bv1.x; a[5] += bv1.y; a[6] += bv1.z; a[7] += bv1.w;

  float s = 0.f, ss = 0.f;
#pragma unroll
  for (int j = 0; j < 8; ++j) { s += a[j]; ss += a[j] * a[j]; }
#pragma unroll
  for (int d = 1; d < 16; d <<= 1) {
    s += __shfl_xor(s, d);
    ss += __shfl_xor(ss, d);
  }
  float mu = s * (1.0f / C_OUT);
  float var = ss * (1.0f / C_OUT) - mu * mu;
  float rs = rsqrtf(var + 1e-5f);
  float4 g0 = *(const float4*)&gamma[c];
  float4 g1 = *(const float4*)&gamma[c + 4];
  float4 t0 = *(const float4*)&beta[c];
  float4 t1 = *(const float4*)&beta[c + 4];
  float o[8];
  o[0] = fmaxf((a[0] - mu) * rs * g0.x + t0.x, 0.0f);
  o[1] = fmaxf((a[1] - mu) * rs * g0.y + t0.y, 0.0f);
  o[2] = fmaxf((a[2] - mu) * rs * g0.z + t0.z, 0.0f);
  o[3] = fmaxf((a[3] - mu) * rs * g0.w + t0.w, 0.0f);
  o[4] = fmaxf((a[4] - mu) * rs * g1.x + t1.x, 0.0f);
  o[5] = fmaxf((a[5] - mu) * rs * g1.y + t1.y, 0.0f);
  o[6] = fmaxf((a[6] - mu) * rs * g1.z + t1.z, 0.0f);
  o[7] = fmaxf((a[7] - mu) * rs * g1.w + t1.w, 0.0f);
  uint4 ov;
  ov.x = pack_bf2(o[0], o[1]); ov.y = pack_bf2(o[2], o[3]);
  ov.z = pack_bf2(o[4], o[5]); ov.w = pack_bf2(o[6], o[7]);
  zb4[(size_t)g * 16 + sl] = ov;
}

// ---------------- Decode: 32-lane group per pair, float4 loads --------------

__global__ __launch_bounds__(256) void decode_kernel(const float4* __restrict__ z4,
                                                     const int* __restrict__ eli,
                                                     const float* __restrict__ cutoff,
                                                     float* __restrict__ out, int EL) {
  int g = (blockIdx.x * 256 + threadIdx.x) >> 5;
  int sl = threadIdx.x & 31;
  if (g >= EL) return;
  int a = eli[g];
  int b = eli[EL + g];
  float4 va = z4[(size_t)a * 32 + sl];
  float4 vb = z4[(size_t)b * 32 + sl];
  float s = va.x * vb.x + va.y * vb.y + va.z * vb.z + va.w * vb.w;
#pragma unroll
  for (int d = 1; d < 32; d <<= 1) s += __shfl_xor(s, d);
  if (sl == 0) {
    out[g] = s;
    out[EL + g] = (s < cutoff[0]) ? 0.0f : 1.0f;
  }
}

// ---------------- Launch ----------------

extern "C" void kernel_launch(void* const* d_in, const int* in_sizes, int n_in,
                              void* d_out, int out_size, void* d_ws, size_t ws_size,
                              hipStream_t stream) {
  const float* x        = (const float*)d_in[0];
  const int*   eidx     = (const int*)d_in[1];
  const int*   eli      = (const int*)d_in[2];
  const float* cutoff   = (const float*)d_in[3];
  const float* W1       = (const float*)d_in[4];
  const float* b1       = (const float*)d_in[5];
  const float* bn_gamma = (const float*)d_in[6];
  const float* bn_beta  = (const float*)d_in[7];
  const float* W2       = (const float*)d_in[8];
  const float* b2       = (const float*)d_in[9];
  const float* ln_gamma = (const float*)d_in[10];
  const float* ln_beta  = (const float*)d_in[11];
  const float* lin_W    = (const float*)d_in[12];
  const float* lin_b    = (const float*)d_in[13];
  float* out = (float*)d_out;

  const int N  = in_sizes[0] / C_IN;   // 100000
  const int E  = in_sizes[1] / 2;      // 800000
  const int EL = in_sizes[2] / 2;      // 200000

  const int* src = eidx;
  const int* dst = eidx + E;

  const int MB = (N + 127) / 128;
  const int R  = 2 * MB;

  // workspace layout
  char* p = (char*)d_ws;
  short* regionA = (short*)p;  p += (size_t)N * 256 * 2;  // x_bf+xa_bf, later h1n_bf
  short* regionB = (short*)p;  p += (size_t)N * 256 * 2;  // h1_bf, later z_bf
  short* h2_bf   = (short*)p;  p += (size_t)N * 128 * 2;
  float* zfin    = (float*)p;  p += (size_t)N * 128 * 4;
  float* dinv    = (float*)p;  p += (size_t)N * 4;
  int* counts    = (int*)p;    p += (size_t)N * 4;
  int* row_ptr   = (int*)p;    p += (size_t)(N + 4) * 4;
  int* cursor    = (int*)p;    p += (size_t)N * 4;
  int2* edges    = (int2*)p;   p += (size_t)E * 8;
  float* pS      = (float*)p;  p += (size_t)R * C_HID * 4;
  float* pSS     = (float*)p;  p += (size_t)R * C_HID * 4;
  float* oS      = (float*)p;  p += 32 * C_HID * 4;
  float* oSS     = (float*)p;  p += 32 * C_HID * 4;
  float* bnp     = (float*)p;  p += 2 * C_HID * 4;
  int* blockSums = (int*)p;    p += SCAN_B * 4;
  int* blockOffs = (int*)p;    p += SCAN_B * 4;
  short* w1t     = (short*)p;  p += (size_t)C_HID * C_IN * 2;
  short* w2t     = (short*)p;  p += (size_t)C_OUT * C_HID * 2;
  short* w3t     = (short*)p;  p += (size_t)C_OUT * C_OUT * 2;

  short* x_bf   = regionA;
  short* xa_bf  = regionA + (size_t)N * 128;
  short* h1_bf  = regionB;
  short* h1n_bf = regionA;
  short* z_bf   = regionB;

  hipMemsetAsync(counts, 0, (size_t)N * 4, stream);

  int eb = (E + 255) / 256;
  int nb = (N + 255) / 256;

  hist_kernel<<<eb, 256, 0, stream>>>(dst, counts, E);
  dinv_kernel<<<nb, 256, 0, stream>>>(counts, dinv, cursor, N);

  int per = (N + 1 + SCAN_B - 1) / SCAN_B;
  scan_part<<<SCAN_B, 256, 0, stream>>>(counts, blockSums, N, per);
  scan_bsums<<<1, 256, 0, stream>>>(blockSums, blockOffs, SCAN_B);
  scan_final<<<SCAN_B, 256, 0, stream>>>(counts, blockOffs, row_ptr, N, per);

  place_kernel<<<eb, 256, 0, stream>>>(src, dst, row_ptr, cursor, dinv, edges, E);

  cvt_wT_kernel<<<(C_IN * C_HID + 255) / 256, 256, 0, stream>>>(W1, w1t, C_IN, C_HID);
  cvt_wT_kernel<<<(C_HID * C_OUT + 255) / 256, 256, 0, stream>>>(W2, w2t, C_HID, C_OUT);
  cvt_wT_kernel<<<(C_OUT * C_OUT + 255) / 256, 256, 0, stream>>>(lin_W, w3t, C_OUT, C_OUT);

  int xn4 = N * C_IN / 4;
  cvt_bf16_kernel<<<(xn4 + 255) / 256, 256, 0, stream>>>(x, x_bf, xn4);

  int gb = ((size_t)N * 16 + 255) / 256;  // 16-lane group per node
  agg_x_kernel<<<gb, 256, 0, stream>>>((const uint4*)x_bf, dinv, row_ptr, edges,
                                       (uint4*)xa_bf, N);

  // GEMM1: h1 = agg(x) @ W1 + b1  [N x 256] bf16 + BN partials
  dim3 g1(C_HID / 128, MB);
  bgemm_big<2><<<g1, 256, 0, stream>>>(xa_bf, w1t, b1, h1_bf, pS, pSS, N, C_HID, C_IN);

  bn_red1_kernel<<<32, 256, 0, stream>>>(pS, pSS, oS, oSS, R);
  bn_red2_kernel<<<1, 256, 0, stream>>>(oS, oSS, bn_gamma, bn_beta, bnp, 32,
                                        1.0f / (float)N);

  int bnb = ((size_t)N * 128 + 255) / 256;
  bn_apply_kernel<<<bnb, 256, 0, stream>>>((const uint32_t*)h1_bf, bnp,
                                           (uint32_t*)h1n_bf, N * 128);

  // GEMM2: h2raw = h1n @ W2  [N x 128] bf16 (bias b2 added in agg_ln)
  dim3 g2(C_OUT / 128, MB);
  bgemm_big<1><<<g2, 256, 0, stream>>>(h1n_bf, w2t, nullptr, h2_bf, nullptr, nullptr,
                                       N, C_OUT, C_HID);

  agg_ln_kernel<<<gb, 256, 0, stream>>>((const uint4*)h2_bf, dinv, row_ptr, edges,
                                        b2, ln_gamma, ln_beta, (uint4*)z_bf, N);

  // GEMM3: zfin = z @ lin_W + lin_b  [N x 128] f32
  dim3 g3(C_OUT / 128, MB);
  bgemm_big<0><<<g3, 256, 0, stream>>>(z_bf, w3t, lin_b, zfin, nullptr, nullptr,
                                       N, C_OUT, C_OUT);

  int db = ((size_t)EL * 32 + 255) / 256;  // 32-lane group per pair
  decode_kernel<<<db, 256, 0, stream>>>((const float4*)zfin, eli, cutoff, out, EL);
}

// Round 7
// 369.401 us; speedup vs baseline: 2.7636x; 1.1685x over previous
//
#include <hip/hip_runtime.h>
#include <stdint.h>

// ---------------------------------------------------------------------------
// Net_60129542953 R7:
//  - place de-atomized: hist records per-edge slot ofs[e]; place is pure
//    compute+scatter (R6's random atomicAdd-return chain was 45us).
//  - bn_apply kernel eliminated: BN scale/shift+ReLU fused into GEMM2's
//    A-staging (A read exactly once there).
//  - GEMM3 output + decode in bf16 (halved write + gather traffic; safe:
//    z>=0 so output-1 thresholding is unaffected).
//  - 3 weight-convert launches merged into 1.
// ---------------------------------------------------------------------------

#define C_IN  128
#define C_HID 256
#define C_OUT 128
#define SCAN_B 256

typedef __attribute__((ext_vector_type(8))) short bf16x8;
typedef __attribute__((ext_vector_type(4))) float f32x4;

__device__ __forceinline__ short f2bf(float f) {
  union { float f; uint32_t u; } v; v.f = f;
  uint32_t r = v.u + 0x7FFFu + ((v.u >> 16) & 1u);  // RNE
  return (short)(r >> 16);
}
__device__ __forceinline__ uint32_t pack_bf2(float a, float b) {
  return (uint32_t)(uint16_t)f2bf(a) | ((uint32_t)(uint16_t)f2bf(b) << 16);
}
__device__ __forceinline__ float bflo(uint32_t p) {
  union { uint32_t u; float f; } v; v.u = p << 16; return v.f;
}
__device__ __forceinline__ float bfhi(uint32_t p) {
  union { uint32_t u; float f; } v; v.u = p & 0xffff0000u; return v.f;
}
__device__ __forceinline__ float bfs(short s) {
  union { uint32_t u; float f; } v; v.u = ((uint32_t)(uint16_t)s) << 16; return v.f;
}

__device__ __forceinline__ void acc8(float* a, uint4 p, float w) {
  a[0] += bflo(p.x) * w; a[1] += bfhi(p.x) * w;
  a[2] += bflo(p.y) * w; a[3] += bfhi(p.y) * w;
  a[4] += bflo(p.z) * w; a[5] += bfhi(p.z) * w;
  a[6] += bflo(p.w) * w; a[7] += bfhi(p.w) * w;
}

__device__ __forceinline__ void async_cp16(const void* g, void* l) {
  __builtin_amdgcn_global_load_lds((const __attribute__((address_space(1))) void*)g,
                                   (__attribute__((address_space(3))) void*)l, 16, 0, 0);
}

// ---------------- CSR build ----------------

// hist also records each edge's slot within its dst bucket
__global__ __launch_bounds__(256) void hist_kernel(const int* __restrict__ dst,
                                                   int* __restrict__ counts,
                                                   int* __restrict__ ofs, int E) {
  int e = blockIdx.x * 256 + threadIdx.x;
  if (e < E) ofs[e] = atomicAdd(&counts[dst[e]], 1);
}

__global__ __launch_bounds__(256) void dinv_kernel(const int* __restrict__ counts,
                                                   float* __restrict__ dinv, int N) {
  int n = blockIdx.x * 256 + threadIdx.x;
  if (n < N) dinv[n] = rsqrtf((float)counts[n] + 1.0f);  // deg = indeg + 1
}

// ---- 3-phase device-wide exclusive scan of counts[0..n) into row_ptr[0..n] --

__global__ __launch_bounds__(256) void scan_part(const int* __restrict__ counts,
                                                 int* __restrict__ blockSums,
                                                 int n, int per) {
  __shared__ int ws[4];
  int b = blockIdx.x;
  int start = b * per, end = min(n, start + per);
  int s = 0;
  for (int i = start + threadIdx.x; i < end; i += 256) s += counts[i];
#pragma unroll
  for (int d = 1; d < 64; d <<= 1) s += __shfl_xor(s, d);
  if ((threadIdx.x & 63) == 0) ws[threadIdx.x >> 6] = s;
  __syncthreads();
  if (threadIdx.x == 0) blockSums[b] = ws[0] + ws[1] + ws[2] + ws[3];
}

__global__ __launch_bounds__(256) void scan_bsums(const int* __restrict__ blockSums,
                                                  int* __restrict__ blockOffs, int B) {
  __shared__ int wsum[4];
  int tid = threadIdx.x, lane = tid & 63, wid = tid >> 6;
  int v = (tid < B) ? blockSums[tid] : 0;
  int x = v;
#pragma unroll
  for (int d = 1; d < 64; d <<= 1) {
    int y = __shfl_up(x, d, 64);
    if (lane >= d) x += y;
  }
  if (lane == 63) wsum[wid] = x;
  __syncthreads();
  if (tid == 0) {
    int run = 0;
#pragma unroll
    for (int w = 0; w < 4; ++w) { int t = wsum[w]; wsum[w] = run; run += t; }
  }
  __syncthreads();
  if (tid < B) blockOffs[tid] = wsum[wid] + x - v;
}

__global__ __launch_bounds__(256) void scan_final(const int* __restrict__ counts,
                                                  const int* __restrict__ blockOffs,
                                                  int* __restrict__ row_ptr,
                                                  int n, int per) {
  __shared__ int wsum[4];
  __shared__ int sbase;
  int tid = threadIdx.x, lane = tid & 63, wid = tid >> 6;
  int b = blockIdx.x;
  int start = b * per, end = min(n + 1, start + per);
  if (tid == 0) sbase = blockOffs[b];
  __syncthreads();
  for (int chunk = start; chunk < end; chunk += 256) {
    int idx = chunk + tid;
    int v = (idx < n) ? counts[idx] : 0;
    int x = v;
#pragma unroll
    for (int d = 1; d < 64; d <<= 1) {
      int y = __shfl_up(x, d, 64);
      if (lane >= d) x += y;
    }
    if (lane == 63) wsum[wid] = x;
    __syncthreads();
    if (tid == 0) {
      int run = sbase;
#pragma unroll
      for (int w = 0; w < 4; ++w) { int t = wsum[w]; wsum[w] = run; run += t; }
      sbase = run;
    }
    __syncthreads();
    if (idx < end) row_ptr[idx] = wsum[wid] + x - v;
    __syncthreads();
  }
}

// edges[row_ptr[d]+ofs[e]] = {src, dinv[src]*dinv[dst]}  (no atomics)
__global__ __launch_bounds__(256) void place_kernel(const int* __restrict__ src,
                                                    const int* __restrict__ dst,
                                                    const int* __restrict__ row_ptr,
                                                    const int* __restrict__ ofs,
                                                    const float* __restrict__ dinv,
                                                    int2* __restrict__ edges, int E) {
  int e = blockIdx.x * 256 + threadIdx.x;
  if (e < E) {
    int d = dst[e], s = src[e];
    int pos = row_ptr[d] + ofs[e];
    int2 ed; ed.x = s; ed.y = __float_as_int(dinv[s] * dinv[d]);
    edges[pos] = ed;
  }
}

// ---------------- Conversions ----------------

__global__ __launch_bounds__(256) void cvt_bf16_kernel(const float* __restrict__ in,
                                                       short* __restrict__ out, int n4) {
  int i = blockIdx.x * 256 + threadIdx.x;
  if (i >= n4) return;
  float4 v = ((const float4*)in)[i];
  short4 o;
  o.x = f2bf(v.x); o.y = f2bf(v.y); o.z = f2bf(v.z); o.w = f2bf(v.w);
  ((short4*)out)[i] = o;
}

// all three weights transpose+convert in one launch.
// W1:128x256 -> w1t[256][128]; W2:256x128 -> w2t[128][256]; W3:128x128 -> w3t[128][128]
__global__ __launch_bounds__(256) void cvt_w_all(const float* __restrict__ W1,
                                                 short* __restrict__ w1t,
                                                 const float* __restrict__ W2,
                                                 short* __restrict__ w2t,
                                                 const float* __restrict__ W3,
                                                 short* __restrict__ w3t) {
  int i = blockIdx.x * 256 + threadIdx.x;
  if (i < 32768) {                       // W1 [k=128][n=256]
    int k = i >> 8, n = i & 255;
    w1t[n * 128 + k] = f2bf(W1[i]);
  } else if (i < 65536) {                // W2 [k=256][n=128]
    int j = i - 32768; int k = j >> 7, n = j & 127;
    w2t[n * 256 + k] = f2bf(W2[j]);
  } else if (i < 81920) {                // W3 [k=128][n=128]
    int j = i - 65536; int k = j >> 7, n = j & 127;
    w3t[n * 128 + k] = f2bf(W3[j]);
  }
}

// ---------------- bf16 MFMA GEMM: C[M,N] = A[M,K] @ BT[N,K]^T (+bias) -------
// 128x128 tile, BK=128, XOR-swizzled LDS, LDS-staged coalesced bf16 C stores.
// MODE 1: plain; MODE 2: + non-atomic BN partials; MODE 3: BN-apply+ReLU
// fused into A staging (A' = relu(A*sc+sh), sc/sh from bnp[0..K),bnp[K..2K)).

template <int MODE>
__global__ __launch_bounds__(256, 2) void bgemm_big(const short* __restrict__ A,
                                                    const short* __restrict__ BT,
                                                    const float* __restrict__ bias,
                                                    short* __restrict__ Cout,
                                                    float* __restrict__ pS,
                                                    float* __restrict__ pSS,
                                                    const float* __restrict__ bnp,
                                                    int M, int N, int K) {
  __shared__ short smem[2 * 128 * 128];  // 64 KB
  short* As = smem;
  short* Bs = smem + 128 * 128;
  const int tid = threadIdx.x;
  const int w = tid >> 6, lane = tid & 63;
  const int wM = w >> 1, wN = w & 1;
  const int rowBase = blockIdx.y * 128;
  const int colBase = blockIdx.x * 128;
  const int l15 = lane & 15, q = lane >> 4;

  f32x4 acc[4][4];
#pragma unroll
  for (int i = 0; i < 4; ++i)
#pragma unroll
    for (int j = 0; j < 4; ++j) acc[i][j] = (f32x4){0.f, 0.f, 0.f, 0.f};

  for (int k0 = 0; k0 < K; k0 += 128) {
    if (MODE == 3) {
      // manual A staging with fused BN+ReLU
#pragma unroll
      for (int it = 0; it < 8; ++it) {
        int p = it * 256 + tid;
        int row = p >> 4, kcp = p & 15;
        int kc = kcp ^ (row & 15);
        int gm = rowBase + row; if (gm >= M) gm = M - 1;
        int c = k0 + kc * 8;
        bf16x8 av = *(const bf16x8*)&A[(size_t)gm * K + c];
        float4 s0 = *(const float4*)&bnp[c];
        float4 s1 = *(const float4*)&bnp[c + 4];
        float4 h0 = *(const float4*)&bnp[K + c];
        float4 h1 = *(const float4*)&bnp[K + c + 4];
        short res[8];
        res[0] = f2bf(fmaxf(bfs(av[0]) * s0.x + h0.x, 0.f));
        res[1] = f2bf(fmaxf(bfs(av[1]) * s0.y + h0.y, 0.f));
        res[2] = f2bf(fmaxf(bfs(av[2]) * s0.z + h0.z, 0.f));
        res[3] = f2bf(fmaxf(bfs(av[3]) * s0.w + h0.w, 0.f));
        res[4] = f2bf(fmaxf(bfs(av[4]) * s1.x + h1.x, 0.f));
        res[5] = f2bf(fmaxf(bfs(av[5]) * s1.y + h1.y, 0.f));
        res[6] = f2bf(fmaxf(bfs(av[6]) * s1.z + h1.z, 0.f));
        res[7] = f2bf(fmaxf(bfs(av[7]) * s1.w + h1.w, 0.f));
        bf16x8 rv;
#pragma unroll
        for (int j = 0; j < 8; ++j) rv[j] = res[j];
        *(bf16x8*)&As[p * 8] = rv;
      }
    } else {
#pragma unroll
      for (int it = 0; it < 8; ++it) {
        int p = it * 256 + tid;
        int row = p >> 4, kcp = p & 15;
        int kc = kcp ^ (row & 15);
        int gm = rowBase + row; if (gm >= M) gm = M - 1;  // clamp; stores guarded
        async_cp16(A + (size_t)gm * K + k0 + kc * 8, &As[(it * 256 + w * 64) * 8]);
      }
    }
#pragma unroll
    for (int it = 0; it < 8; ++it) {
      int p = it * 256 + tid;
      int row = p >> 4, kcp = p & 15;
      int kc = kcp ^ (row & 15);
      async_cp16(BT + (size_t)(colBase + row) * K + k0 + kc * 8,
                 &Bs[(it * 256 + w * 64) * 8]);
    }
    __syncthreads();  // drains async (vmcnt) + ds_write (lgkmcnt)

#pragma unroll
    for (int ks = 0; ks < 4; ++ks) {
      bf16x8 af[4], bfr[4];
#pragma unroll
      for (int tm = 0; tm < 4; ++tm) {
        int row = wM * 64 + tm * 16 + l15;
        int kcp = (ks * 4 + q) ^ l15;
        af[tm] = *(const bf16x8*)&As[(row * 16 + kcp) * 8];
      }
#pragma unroll
      for (int tn = 0; tn < 4; ++tn) {
        int row = wN * 64 + tn * 16 + l15;
        int kcp = (ks * 4 + q) ^ l15;
        bfr[tn] = *(const bf16x8*)&Bs[(row * 16 + kcp) * 8];
      }
#pragma unroll
      for (int tm = 0; tm < 4; ++tm)
#pragma unroll
        for (int tn = 0; tn < 4; ++tn)
          acc[tm][tn] = __builtin_amdgcn_mfma_f32_16x16x32_bf16(af[tm], bfr[tn],
                                                                acc[tm][tn], 0, 0, 0);
    }
    __syncthreads();
  }

  if (MODE == 2) {
#pragma unroll
    for (int tn = 0; tn < 4; ++tn) {
      int col = colBase + wN * 64 + tn * 16 + l15;
      float bv = bias ? bias[col] : 0.0f;
      float s = 0.f, ss = 0.f;
#pragma unroll
      for (int tm = 0; tm < 4; ++tm) {
        int r0 = rowBase + wM * 64 + tm * 16 + q * 4;
#pragma unroll
        for (int r = 0; r < 4; ++r) {
          if (r0 + r < M) { float v = acc[tm][tn][r] + bv; s += v; ss += v * v; }
        }
      }
      s += __shfl_xor(s, 16); s += __shfl_xor(s, 32);
      ss += __shfl_xor(ss, 16); ss += __shfl_xor(ss, 32);
      if (q == 0) {
        int prow = blockIdx.y * 2 + wM;
        pS[(size_t)prow * C_HID + col] = s;
        pSS[(size_t)prow * C_HID + col] = ss;
      }
    }
  }

  // bf16 epilogue: stage tile in LDS, coalesced dwordx4 stores
  {
    short* S = As;
#pragma unroll
    for (int tn = 0; tn < 4; ++tn) {
      int col = wN * 64 + tn * 16 + l15;
      float bv = bias ? bias[colBase + col] : 0.0f;
#pragma unroll
      for (int tm = 0; tm < 4; ++tm) {
        int r0 = wM * 64 + tm * 16 + q * 4;
#pragma unroll
        for (int r = 0; r < 4; ++r) S[(r0 + r) * 128 + col] = f2bf(acc[tm][tn][r] + bv);
      }
    }
    __syncthreads();
#pragma unroll
    for (int it = 0; it < 8; ++it) {
      int p = it * 256 + tid;
      int row = p >> 4, c = p & 15;
      int gm = rowBase + row;
      if (gm < M)
        *(uint4*)&Cout[(size_t)gm * N + colBase + c * 8] = ((const uint4*)S)[p];
    }
  }
}

// ---------------- BN stats tree reduce ----------------

__global__ __launch_bounds__(256) void bn_red1_kernel(const float* __restrict__ pS,
                                                      const float* __restrict__ pSS,
                                                      float* __restrict__ oS,
                                                      float* __restrict__ oSS, int R) {
  int c = threadIdx.x;
  int per = (R + gridDim.x - 1) / gridDim.x;
  int r0 = blockIdx.x * per, r1 = min(R, r0 + per);
  float s = 0.f, ss = 0.f;
  for (int r = r0; r < r1; ++r) {
    s += pS[(size_t)r * C_HID + c];
    ss += pSS[(size_t)r * C_HID + c];
  }
  oS[(size_t)blockIdx.x * C_HID + c] = s;
  oSS[(size_t)blockIdx.x * C_HID + c] = ss;
}

__global__ __launch_bounds__(256) void bn_red2_kernel(const float* __restrict__ oS,
                                                      const float* __restrict__ oSS,
                                                      const float* __restrict__ gamma,
                                                      const float* __restrict__ beta,
                                                      float* __restrict__ bnp,
                                                      int G, float invN) {
  int c = threadIdx.x;
  float s = 0.f, ss = 0.f;
  for (int g = 0; g < G; ++g) {
    s += oS[(size_t)g * C_HID + c];
    ss += oSS[(size_t)g * C_HID + c];
  }
  float mu = s * invN;
  float var = ss * invN - mu * mu;
  float sc = gamma[c] * rsqrtf(var + 1e-5f);
  bnp[c] = sc;
  bnp[C_HID + c] = beta[c] - mu * sc;
}

// ---------------- Aggregations: 16-lane group per node, unroll x4 ----------

__global__ __launch_bounds__(256) void agg_x_kernel(const uint4* __restrict__ xb4,
                                                    const float* __restrict__ dinv,
                                                    const int* __restrict__ row_ptr,
                                                    const int2* __restrict__ edges,
                                                    uint4* __restrict__ out4, int N) {
  int g = (blockIdx.x * 256 + threadIdx.x) >> 4;
  int sl = threadIdx.x & 15;
  if (g >= N) return;
  int e0 = row_ptr[g], e1 = row_ptr[g + 1];
  float a[8] = {0.f, 0.f, 0.f, 0.f, 0.f, 0.f, 0.f, 0.f};
  int e = e0;
  for (; e + 4 <= e1; e += 4) {
    int2 ed0 = edges[e], ed1 = edges[e + 1], ed2 = edges[e + 2], ed3 = edges[e + 3];
    uint4 p0 = xb4[(size_t)ed0.x * 16 + sl];
    uint4 p1 = xb4[(size_t)ed1.x * 16 + sl];
    uint4 p2 = xb4[(size_t)ed2.x * 16 + sl];
    uint4 p3 = xb4[(size_t)ed3.x * 16 + sl];
    acc8(a, p0, __int_as_float(ed0.y));
    acc8(a, p1, __int_as_float(ed1.y));
    acc8(a, p2, __int_as_float(ed2.y));
    acc8(a, p3, __int_as_float(ed3.y));
  }
  for (; e < e1; ++e) {
    int2 ed = edges[e];
    uint4 p = xb4[(size_t)ed.x * 16 + sl];
    acc8(a, p, __int_as_float(ed.y));
  }
  float dn = dinv[g];
  uint4 ps = xb4[(size_t)g * 16 + sl];
  acc8(a, ps, dn * dn);
  uint4 o;
  o.x = pack_bf2(a[0], a[1]); o.y = pack_bf2(a[2], a[3]);
  o.z = pack_bf2(a[4], a[5]); o.w = pack_bf2(a[6], a[7]);
  out4[(size_t)g * 16 + sl] = o;
}

__global__ __launch_bounds__(256) void agg_ln_kernel(const uint4* __restrict__ hb4,
                                                     const float* __restrict__ dinv,
                                                     const int* __restrict__ row_ptr,
                                                     const int2* __restrict__ edges,
                                                     const float* __restrict__ bias,
                                                     const float* __restrict__ gamma,
                                                     const float* __restrict__ beta,
                                                     uint4* __restrict__ zb4, int N) {
  int g = (blockIdx.x * 256 + threadIdx.x) >> 4;
  int sl = threadIdx.x & 15;
  if (g >= N) return;
  int e0 = row_ptr[g], e1 = row_ptr[g + 1];
  float a[8] = {0.f, 0.f, 0.f, 0.f, 0.f, 0.f, 0.f, 0.f};
  int e = e0;
  for (; e + 4 <= e1; e += 4) {
    int2 ed0 = edges[e], ed1 = edges[e + 1], ed2 = edges[e + 2], ed3 = edges[e + 3];
    uint4 p0 = hb4[(size_t)ed0.x * 16 + sl];
    uint4 p1 = hb4[(size_t)ed1.x * 16 + sl];
    uint4 p2 = hb4[(size_t)ed2.x * 16 + sl];
    uint4 p3 = hb4[(size_t)ed3.x * 16 + sl];
    acc8(a, p0, __int_as_float(ed0.y));
    acc8(a, p1, __int_as_float(ed1.y));
    acc8(a, p2, __int_as_float(ed2.y));
    acc8(a, p3, __int_as_float(ed3.y));
  }
  for (; e < e1; ++e) {
    int2 ed = edges[e];
    uint4 p = hb4[(size_t)ed.x * 16 + sl];
    acc8(a, p, __int_as_float(ed.y));
  }
  float dn = dinv[g];
  uint4 ps = hb4[(size_t)g * 16 + sl];
  acc8(a, ps, dn * dn);

  int c = sl * 8;
  float4 bv0 = *(const float4*)&bias[c];
  float4 bv1 = *(const float4*)&bias[c + 4];
  a[0] += bv0.x; a[1] += bv0.y; a[2] += bv0.z; a[3] += bv0.w;
  a[4] += bv1.x; a[5] += bv1.y; a[6] += bv1.z; a[7] += bv1.w;

  float s = 0.f, ss = 0.f;
#pragma unroll
  for (int j = 0; j < 8; ++j) { s += a[j]; ss += a[j] * a[j]; }
#pragma unroll
  for (int d = 1; d < 16; d <<= 1) {
    s += __shfl_xor(s, d);
    ss += __shfl_xor(ss, d);
  }
  float mu = s * (1.0f / C_OUT);
  float var = ss * (1.0f / C_OUT) - mu * mu;
  float rs = rsqrtf(var + 1e-5f);
  float4 g0 = *(const float4*)&gamma[c];
  float4 g1 = *(const float4*)&gamma[c + 4];
  float4 t0 = *(const float4*)&beta[c];
  float4 t1 = *(const float4*)&beta[c + 4];
  float o[8];
  o[0] = fmaxf((a[0] - mu) * rs * g0.x + t0.x, 0.0f);
  o[1] = fmaxf((a[1] - mu) * rs * g0.y + t0.y, 0.0f);
  o[2] = fmaxf((a[2] - mu) * rs * g0.z + t0.z, 0.0f);
  o[3] = fmaxf((a[3] - mu) * rs * g0.w + t0.w, 0.0f);
  o[4] = fmaxf((a[4] - mu) * rs * g1.x + t1.x, 0.0f);
  o[5] = fmaxf((a[5] - mu) * rs * g1.y + t1.y, 0.0f);
  o[6] = fmaxf((a[6] - mu) * rs * g1.z + t1.z, 0.0f);
  o[7] = fmaxf((a[7] - mu) * rs * g1.w + t1.w, 0.0f);
  uint4 ov;
  ov.x = pack_bf2(o[0], o[1]); ov.y = pack_bf2(o[2], o[3]);
  ov.z = pack_bf2(o[4], o[5]); ov.w = pack_bf2(o[6], o[7]);
  zb4[(size_t)g * 16 + sl] = ov;
}

// ---------------- Decode: 16-lane group per pair, bf16 z rows ---------------

__global__ __launch_bounds__(256) void decode_kernel(const uint4* __restrict__ zb4,
                                                     const int* __restrict__ eli,
                                                     const float* __restrict__ cutoff,
                                                     float* __restrict__ out, int EL) {
  int g = (blockIdx.x * 256 + threadIdx.x) >> 4;
  int sl = threadIdx.x & 15;
  if (g >= EL) return;
  int a = eli[g];
  int b = eli[EL + g];
  uint4 va = zb4[(size_t)a * 16 + sl];
  uint4 vb = zb4[(size_t)b * 16 + sl];
  float s = bflo(va.x) * bflo(vb.x) + bfhi(va.x) * bfhi(vb.x)
          + bflo(va.y) * bflo(vb.y) + bfhi(va.y) * bfhi(vb.y)
          + bflo(va.z) * bflo(vb.z) + bfhi(va.z) * bfhi(vb.z)
          + bflo(va.w) * bflo(vb.w) + bfhi(va.w) * bfhi(vb.w);
#pragma unroll
  for (int d = 1; d < 16; d <<= 1) s += __shfl_xor(s, d);
  if (sl == 0) {
    out[g] = s;
    out[EL + g] = (s < cutoff[0]) ? 0.0f : 1.0f;
  }
}

// ---------------- Launch ----------------

extern "C" void kernel_launch(void* const* d_in, const int* in_sizes, int n_in,
                              void* d_out, int out_size, void* d_ws, size_t ws_size,
                              hipStream_t stream) {
  const float* x        = (const float*)d_in[0];
  const int*   eidx     = (const int*)d_in[1];
  const int*   eli      = (const int*)d_in[2];
  const float* cutoff   = (const float*)d_in[3];
  const float* W1       = (const float*)d_in[4];
  const float* b1       = (const float*)d_in[5];
  const float* bn_gamma = (const float*)d_in[6];
  const float* bn_beta  = (const float*)d_in[7];
  const float* W2       = (const float*)d_in[8];
  const float* b2       = (const float*)d_in[9];
  const float* ln_gamma = (const float*)d_in[10];
  const float* ln_beta  = (const float*)d_in[11];
  const float* lin_W    = (const float*)d_in[12];
  const float* lin_b    = (const float*)d_in[13];
  float* out = (float*)d_out;

  const int N  = in_sizes[0] / C_IN;   // 100000
  const int E  = in_sizes[1] / 2;      // 800000
  const int EL = in_sizes[2] / 2;      // 200000

  const int* src = eidx;
  const int* dst = eidx + E;

  const int MB = (N + 127) / 128;
  const int R  = 2 * MB;

  // workspace layout
  char* p = (char*)d_ws;
  short* regionA = (short*)p;  p += (size_t)N * 256 * 2;  // x_bf+xa_bf, later zf_bf
  short* regionB = (short*)p;  p += (size_t)N * 256 * 2;  // h1_bf, later z_bf
  short* h2_bf   = (short*)p;  p += (size_t)N * 128 * 2;
  float* dinv    = (float*)p;  p += (size_t)N * 4;
  int* counts    = (int*)p;    p += (size_t)N * 4;
  int* row_ptr   = (int*)p;    p += (size_t)(N + 4) * 4;
  int* ofs       = (int*)p;    p += (size_t)E * 4;
  int2* edges    = (int2*)p;   p += (size_t)E * 8;
  float* pS      = (float*)p;  p += (size_t)R * C_HID * 4;
  float* pSS     = (float*)p;  p += (size_t)R * C_HID * 4;
  float* oS      = (float*)p;  p += 32 * C_HID * 4;
  float* oSS     = (float*)p;  p += 32 * C_HID * 4;
  float* bnp     = (float*)p;  p += 2 * C_HID * 4;
  int* blockSums = (int*)p;    p += SCAN_B * 4;
  int* blockOffs = (int*)p;    p += SCAN_B * 4;
  short* w1t     = (short*)p;  p += (size_t)C_HID * C_IN * 2;
  short* w2t     = (short*)p;  p += (size_t)C_OUT * C_HID * 2;
  short* w3t     = (short*)p;  p += (size_t)C_OUT * C_OUT * 2;

  short* x_bf   = regionA;                    // [N][128]
  short* xa_bf  = regionA + (size_t)N * 128;  // [N][128]
  short* h1_bf  = regionB;                    // [N][256]
  short* z_bf   = regionB;                    // [N][128] (h1 dead after GEMM2)
  short* zf_bf  = regionA;                    // [N][128] (x/xa dead after GEMM1)

  hipMemsetAsync(counts, 0, (size_t)N * 4, stream);

  int eb = (E + 255) / 256;
  int nb = (N + 255) / 256;

  hist_kernel<<<eb, 256, 0, stream>>>(dst, counts, ofs, E);
  dinv_kernel<<<nb, 256, 0, stream>>>(counts, dinv, N);

  int per = (N + 1 + SCAN_B - 1) / SCAN_B;
  scan_part<<<SCAN_B, 256, 0, stream>>>(counts, blockSums, N, per);
  scan_bsums<<<1, 256, 0, stream>>>(blockSums, blockOffs, SCAN_B);
  scan_final<<<SCAN_B, 256, 0, stream>>>(counts, blockOffs, row_ptr, N, per);

  place_kernel<<<eb, 256, 0, stream>>>(src, dst, row_ptr, ofs, dinv, edges, E);

  cvt_w_all<<<320, 256, 0, stream>>>(W1, w1t, W2, w2t, lin_W, w3t);

  int xn4 = N * C_IN / 4;
  cvt_bf16_kernel<<<(xn4 + 255) / 256, 256, 0, stream>>>(x, x_bf, xn4);

  int gb = ((size_t)N * 16 + 255) / 256;  // 16-lane group per node
  agg_x_kernel<<<gb, 256, 0, stream>>>((const uint4*)x_bf, dinv, row_ptr, edges,
                                       (uint4*)xa_bf, N);

  // GEMM1: h1 = agg(x) @ W1 + b1  [N x 256] bf16 + BN partials
  dim3 g1(C_HID / 128, MB);
  bgemm_big<2><<<g1, 256, 0, stream>>>(xa_bf, w1t, b1, h1_bf, pS, pSS, nullptr,
                                       N, C_HID, C_IN);

  bn_red1_kernel<<<32, 256, 0, stream>>>(pS, pSS, oS, oSS, R);
  bn_red2_kernel<<<1, 256, 0, stream>>>(oS, oSS, bn_gamma, bn_beta, bnp, 32,
                                        1.0f / (float)N);

  // GEMM2: h2raw = relu(bn(h1)) @ W2  [N x 128] bf16; BN fused into A staging
  dim3 g2(C_OUT / 128, MB);
  bgemm_big<3><<<g2, 256, 0, stream>>>(h1_bf, w2t, nullptr, h2_bf, nullptr, nullptr,
                                       bnp, N, C_OUT, C_HID);

  agg_ln_kernel<<<gb, 256, 0, stream>>>((const uint4*)h2_bf, dinv, row_ptr, edges,
                                        b2, ln_gamma, ln_beta, (uint4*)z_bf, N);

  // GEMM3: zf = z @ lin_W + lin_b  [N x 128] bf16
  dim3 g3(C_OUT / 128, MB);
  bgemm_big<1><<<g3, 256, 0, stream>>>(z_bf, w3t, lin_b, zf_bf, nullptr, nullptr,
                                       nullptr, N, C_OUT, C_OUT);

  int db = ((size_t)EL * 16 + 255) / 256;  // 16-lane group per pair
  decode_kernel<<<db, 256, 0, stream>>>((const uint4*)zf_bf, eli, cutoff, out, EL);
}